// Round 4
// baseline (543.912 us; speedup 1.0000x reference)
//
#include <hip/hip_runtime.h>
#include <hip/hip_bf16.h>
#include <math.h>

using bf16 = __hip_bfloat16;
typedef __attribute__((ext_vector_type(8))) short short8;
typedef __attribute__((ext_vector_type(4))) float floatx4;

#define SEQLEN   2048
#define ROWS     4096      // B*L
#define DMODEL   1024
#define DINNER   2048
#define NHEADS   32
#define HEADDIM  64
#define DSTATE   64
#define CONVDIM  2176
#define DINPROJ  4256
#define NCHUNK   32        // 2048 / 64

__device__ __forceinline__ float b2f(bf16 x) { return __bfloat162float(x); }
__device__ __forceinline__ bf16  f2b(float x) { return __float2bfloat16(x); }
__device__ __forceinline__ float s2f(short s) { union { short s; bf16 b; } u; u.s = s; return b2f(u.b); }
__device__ __forceinline__ short f2s(float f) { union { short s; bf16 b; } u; u.b = f2b(f); return u.s; }
__device__ __forceinline__ float tof(float x) { return x; }
__device__ __forceinline__ float tof(bf16 x)  { return __bfloat162float(x); }

// ---------------- async global->LDS (16B per lane) ----------------
typedef __attribute__((address_space(1))) void v_as1;
typedef __attribute__((address_space(3))) void v_as3;
__device__ __forceinline__ void gload_lds16(const void* g, void* l) {
  __builtin_amdgcn_global_load_lds((v_as1*)(g), (v_as3*)(l), 16, 0, 0);
}

// ---------------- fp32 -> bf16 conversion (4 elems/thread) ----------------
__global__ void cvt_kernel(const float* __restrict__ in, bf16* __restrict__ out, int n4) {
  int i = blockIdx.x * 256 + threadIdx.x;
  if (i < n4) {
    float4 v = ((const float4*)in)[i];
    union { bf16 h[4]; uint2 u; } r;
    r.h[0] = f2b(v.x); r.h[1] = f2b(v.y); r.h[2] = f2b(v.z); r.h[3] = f2b(v.w);
    ((uint2*)out)[i] = r.u;
  }
}

// ---------------- block reduction (2 values, 256 threads) ----------------
__device__ __forceinline__ void block_reduce_2(float& a, float& b) {
#pragma unroll
  for (int off = 32; off > 0; off >>= 1) {
    a += __shfl_xor(a, off);
    b += __shfl_xor(b, off);
  }
  __shared__ float ra[4], rb[4];
  int w = threadIdx.x >> 6;
  if ((threadIdx.x & 63) == 0) { ra[w] = a; rb[w] = b; }
  __syncthreads();
  a = ra[0] + ra[1] + ra[2] + ra[3];
  b = rb[0] + rb[1] + rb[2] + rb[3];
}

// ---------------- LayerNorm (1024 cols, fp32/bf16 in, bf16 out) ----------------
template<typename TIN>
__global__ void ln_kernel(const TIN* __restrict__ x, const float* __restrict__ w,
                          const float* __restrict__ b, bf16* __restrict__ out)
{
  int row = blockIdx.x;
  int tid = threadIdx.x;
  float v[4]; float s = 0.f, sq = 0.f;
#pragma unroll
  for (int k = 0; k < 4; ++k) {
    int c = k * 256 + tid;
    float xv = tof(x[(size_t)row * DMODEL + c]);
    v[k] = xv; s += xv; sq += xv * xv;
  }
  block_reduce_2(s, sq);
  float mu  = s * (1.f / DMODEL);
  float var = sq * (1.f / DMODEL) - mu * mu;
  float rs  = rsqrtf(var + 1e-5f);
#pragma unroll
  for (int k = 0; k < 4; ++k) {
    int c = k * 256 + tid;
    out[(size_t)row * DMODEL + c] = f2b((v[k] - mu) * rs * w[c] + b[c]);
  }
}

// ---------------- GEMM: C[M,N] = epi(A[M,K] @ W[N,K]^T), double-buffered LDS ----------------
// EPI 0: store bf16
// EPI 1: +bias(fp32), exact GELU, store bf16
// EPI 2: +resid(fp32), store bf16
// EPI 3: +bias(fp32) +resid(bf16), store fp32
template<int EPI>
__global__ __launch_bounds__(256, 2)
void gemm_bt(const bf16* __restrict__ A, const bf16* __restrict__ W,
             const float* __restrict__ bias, const void* __restrict__ resid,
             void* __restrict__ Cout, int M, int N, int K)
{
  __shared__ __align__(16) short Asl[2][128 * 64];
  __shared__ __align__(16) short Bsl[2][128 * 64];
  const int tid  = threadIdx.x;
  const int lane = tid & 63;
  const int wv   = tid >> 6;
  const int wm   = wv >> 1, wn = wv & 1;
  const int r16  = lane & 15, q = lane >> 4;
  const int m0   = blockIdx.y * 128;
  const int n0   = blockIdx.x * 128;
  const int nk   = K >> 6;

  floatx4 acc[4][4] = {};

  auto stage = [&](int buf, int k0) {
#pragma unroll
    for (int it = 0; it < 4; ++it) {
      int idx = it * 256 + tid;
      int row = m0 + (idx >> 3);
      int cb  = (idx & 7) << 3;
      gload_lds16(A + (size_t)row * K + k0 + cb, &Asl[buf][idx * 8]);
    }
#pragma unroll
    for (int it = 0; it < 4; ++it) {
      int idx = it * 256 + tid;
      int row = n0 + (idx >> 3);
      if (row > N - 1) row = N - 1;   // clamp for N tail tile
      int cb  = (idx & 7) << 3;
      gload_lds16(W + (size_t)row * K + k0 + cb, &Bsl[buf][idx * 8]);
    }
  };

  stage(0, 0);
  for (int k = 0; k < nk; ++k) {
    __syncthreads();                       // drains stage(k); one barrier per iter
    if (k + 1 < nk) stage((k + 1) & 1, (k + 1) << 6);   // async prefetch overlaps MFMA below
    const int cur = k & 1;
#pragma unroll
    for (int kk = 0; kk < 64; kk += 32) {
      short8 af[4], bfr[4];
#pragma unroll
      for (int i = 0; i < 4; ++i)
        af[i] = *(const short8*)&Asl[cur][(wm * 64 + i * 16 + r16) * 64 + kk + q * 8];
#pragma unroll
      for (int j = 0; j < 4; ++j)
        bfr[j] = *(const short8*)&Bsl[cur][(wn * 64 + j * 16 + r16) * 64 + kk + q * 8];
#pragma unroll
      for (int i = 0; i < 4; ++i)
#pragma unroll
        for (int j = 0; j < 4; ++j)
          acc[i][j] = __builtin_amdgcn_mfma_f32_16x16x32_bf16(af[i], bfr[j], acc[i][j], 0, 0, 0);
    }
  }

#pragma unroll
  for (int i = 0; i < 4; ++i) {
#pragma unroll
    for (int j = 0; j < 4; ++j) {
#pragma unroll
      for (int r = 0; r < 4; ++r) {
        int row = m0 + wm * 64 + i * 16 + q * 4 + r;
        int col = n0 + wn * 64 + j * 16 + r16;
        if (col < N) {
          float v = acc[i][j][r];
          size_t off = (size_t)row * N + col;
          if (EPI == 0) {
            ((bf16*)Cout)[off] = f2b(v);
          } else if (EPI == 1) {
            v += bias[col];
            v = 0.5f * v * (1.f + erff(v * 0.70710678118654752f));
            ((bf16*)Cout)[off] = f2b(v);
          } else if (EPI == 2) {
            v += ((const float*)resid)[off];
            ((bf16*)Cout)[off] = f2b(v);
          } else {
            v += bias[col] + b2f(((const bf16*)resid)[off]);
            ((float*)Cout)[off] = v;
          }
        }
      }
    }
  }
}

// ---------------- depthwise causal conv (4 tap) + SiLU + softplus(dt) ----------------
__global__ void conv_kernel(const bf16* __restrict__ zx, const float* __restrict__ cw,
                            const float* __restrict__ cb, const float* __restrict__ dtbias,
                            bf16* __restrict__ xbc, bf16* __restrict__ Bb,
                            bf16* __restrict__ Cbb, float* __restrict__ dtb)
{
  int row = blockIdx.x;
  int b = row >> 11, t = row & 2047;
  for (int c = threadIdx.x; c < CONVDIM; c += 256) {
    float acc = cb[c];
#pragma unroll
    for (int k = 0; k < 4; ++k) {
      int tt = t + k - 3;
      if (tt >= 0)
        acc += b2f(zx[((size_t)(b * SEQLEN + tt)) * DINPROJ + DINNER + c]) * cw[c * 4 + k];
    }
    float s = acc / (1.f + __expf(-acc));   // SiLU
    xbc[(size_t)row * CONVDIM + c] = f2b(s);
    if (c >= DINNER) {
      if (c < DINNER + DSTATE) Bb[row * DSTATE + (c - DINNER)] = f2b(s);
      else                     Cbb[row * DSTATE + (c - DINNER - DSTATE)] = f2b(s);
    }
  }
  if (threadIdx.x < NHEADS) {
    int hh = threadIdx.x;
    float raw = b2f(zx[(size_t)row * DINPROJ + DINNER + CONVDIM + hh]) + dtbias[hh];
    float dt = raw > 20.f ? raw : log1pf(__expf(raw));   // softplus
    dtb[row * NHEADS + hh] = dt;
  }
}

// ---------------- wave inclusive prefix sum helper ----------------
__device__ __forceinline__ float wave_incl_prefix(float a, int lane) {
#pragma unroll
  for (int off = 1; off < 64; off <<= 1) {
    float o = __shfl_up(a, off);
    if (lane >= off) a += o;
  }
  return a;
}

// ---------------- SSD phase A: chunk end-state S = Xw^T @ B, decay P ----------------
__global__ __launch_bounds__(64)
void chunk_state_kernel(const bf16* __restrict__ xbc, const bf16* __restrict__ Bb,
                        const float* __restrict__ dtb, const float* __restrict__ A_log,
                        float* __restrict__ Sbuf, float* __restrict__ Pbuf)
{
  const int blk = blockIdx.x;
  const int c = blk & 31, h = (blk >> 5) & 31, b = blk >> 10;
  const int bh = b * 32 + h;
  const int lane = threadIdx.x;              // = s (timestep within chunk)
  const int row = b * SEQLEN + c * 64 + lane;
  const float Ah = -__expf(A_log[h]);

  float dts = dtb[row * NHEADS + h];
  float E = wave_incl_prefix(dts * Ah, lane);
  float EQ = __shfl(E, 63);
  float w = __expf(EQ - E) * dts;
  if (lane == 63) Pbuf[bh * NCHUNK + c] = __expf(EQ);

  __shared__ __align__(16) short XwT[64 * 72];   // [p][s] pad 72
  __shared__ __align__(16) short BT[64 * 72];    // [n][s] pad 72

  const bf16* xrow = xbc + (size_t)row * CONVDIM + h * 64;
  const bf16* brow = Bb + (size_t)row * DSTATE;
#pragma unroll
  for (int i = 0; i < 8; ++i) {
    short8 xv = *(const short8*)(xrow + i * 8);
    short8 bv = *(const short8*)(brow + i * 8);
#pragma unroll
    for (int j = 0; j < 8; ++j) {
      XwT[(i * 8 + j) * 72 + lane] = f2s(w * s2f(xv[j]));
      BT[(i * 8 + j) * 72 + lane]  = bv[j];
    }
  }
  __syncthreads();

  const int r16 = lane & 15, q = lane >> 4;
  floatx4 acc[4][4] = {};
#pragma unroll
  for (int kk = 0; kk < 64; kk += 32) {
    short8 af[4], bfr[4];
#pragma unroll
    for (int i = 0; i < 4; ++i) af[i]  = *(const short8*)&XwT[(i * 16 + r16) * 72 + kk + q * 8];
#pragma unroll
    for (int j = 0; j < 4; ++j) bfr[j] = *(const short8*)&BT[(j * 16 + r16) * 72 + kk + q * 8];
#pragma unroll
    for (int i = 0; i < 4; ++i)
#pragma unroll
      for (int j = 0; j < 4; ++j)
        acc[i][j] = __builtin_amdgcn_mfma_f32_16x16x32_bf16(af[i], bfr[j], acc[i][j], 0, 0, 0);
  }
  float* Sout = Sbuf + (size_t)(bh * NCHUNK + c) * 4096;
#pragma unroll
  for (int i = 0; i < 4; ++i)
#pragma unroll
    for (int j = 0; j < 4; ++j)
#pragma unroll
      for (int r = 0; r < 4; ++r)
        Sout[(i * 16 + q * 4 + r) * 64 + (j * 16 + r16)] = acc[i][j][r];
}

// ---------------- SSD phase B: serial chunk combine (scalar decay) ----------------
__global__ __launch_bounds__(64)
void combine_kernel(const float* __restrict__ Sbuf, const float* __restrict__ Pbuf,
                    bf16* __restrict__ HinB)
{
  const int bh = blockIdx.x >> 2, slab = blockIdx.x & 3;
  const int base = slab * 1024 + threadIdx.x * 16;
  float h[16];
#pragma unroll
  for (int k = 0; k < 16; ++k) h[k] = 0.f;
  for (int c = 0; c < NCHUNK; ++c) {
    size_t off = (size_t)(bh * NCHUNK + c) * 4096 + base;
    union { short s[16]; uint4 q[2]; } pk;
#pragma unroll
    for (int k = 0; k < 16; ++k) pk.s[k] = f2s(h[k]);
    *(uint4*)(HinB + off)     = pk.q[0];
    *(uint4*)(HinB + off + 8) = pk.q[1];
    float P = Pbuf[bh * NCHUNK + c];
    const float4* S4 = (const float4*)(Sbuf + off);
#pragma unroll
    for (int k = 0; k < 4; ++k) {
      float4 s = S4[k];
      h[k*4+0] = h[k*4+0] * P + s.x;
      h[k*4+1] = h[k*4+1] * P + s.y;
      h[k*4+2] = h[k*4+2] * P + s.z;
      h[k*4+3] = h[k*4+3] * P + s.w;
    }
  }
}

// ---------------- SSD phase C: Y = (mask ⊙ C B^T) @ Xdt + (e^E C) @ Hin^T + D x ----------------
__global__ __launch_bounds__(64)
void y_kernel(const bf16* __restrict__ xbc, const bf16* __restrict__ Bb,
              const bf16* __restrict__ Cbb, const float* __restrict__ dtb,
              const bf16* __restrict__ HinB, const float* __restrict__ A_log,
              const float* __restrict__ Dp, bf16* __restrict__ yout)
{
  const int blk = blockIdx.x;
  const int c = blk & 31, h = (blk >> 5) & 31, b = blk >> 10;
  const int bh = b * 32 + h;
  const int lane = threadIdx.x;              // = s for the builds
  const int row0 = b * SEQLEN + c * 64;
  const int row = row0 + lane;
  const float Ah = -__expf(A_log[h]);
  const float Dh = Dp[h];

  __shared__ __align__(16) short XdT[64 * 72];  // [p][s]
  __shared__ __align__(16) short Msh[64 * 72];  // [t][s]
  __shared__ float Esh[64];

  float dts = dtb[row * NHEADS + h];
  float E = wave_incl_prefix(dts * Ah, lane);
  Esh[lane] = E;

  const bf16* xrow = xbc + (size_t)row * CONVDIM + h * 64;
#pragma unroll
  for (int i = 0; i < 8; ++i) {
    short8 xv = *(const short8*)(xrow + i * 8);
#pragma unroll
    for (int j = 0; j < 8; ++j)
      XdT[(i * 8 + j) * 72 + lane] = f2s(dts * s2f(xv[j]));
  }
  __syncthreads();

  const int r16 = lane & 15, q = lane >> 4;

  // G = C @ B^T  (t x s)
  floatx4 accg[4][4] = {};
#pragma unroll
  for (int kk = 0; kk < 64; kk += 32) {
    short8 af[4], bfr[4];
#pragma unroll
    for (int i = 0; i < 4; ++i)
      af[i]  = *(const short8*)(Cbb + (size_t)(row0 + i * 16 + r16) * DSTATE + kk + q * 8);
#pragma unroll
    for (int j = 0; j < 4; ++j)
      bfr[j] = *(const short8*)(Bb + (size_t)(row0 + j * 16 + r16) * DSTATE + kk + q * 8);
#pragma unroll
    for (int i = 0; i < 4; ++i)
#pragma unroll
      for (int j = 0; j < 4; ++j)
        accg[i][j] = __builtin_amdgcn_mfma_f32_16x16x32_bf16(af[i], bfr[j], accg[i][j], 0, 0, 0);
  }
  // causal decay mask -> Msh (bf16, A-operand layout for next MFMA)
#pragma unroll
  for (int i = 0; i < 4; ++i)
#pragma unroll
    for (int j = 0; j < 4; ++j)
#pragma unroll
      for (int r = 0; r < 4; ++r) {
        int t = i * 16 + q * 4 + r;
        int s = j * 16 + r16;
        float v = (s <= t) ? __expf(Esh[t] - Esh[s]) * accg[i][j][r] : 0.f;
        Msh[t * 72 + s] = f2s(v);
      }
  __syncthreads();

  floatx4 acc[4][4] = {};
  // Y_intra = M @ Xdt   (t x p)
#pragma unroll
  for (int kk = 0; kk < 64; kk += 32) {
    short8 af[4], bfr[4];
#pragma unroll
    for (int i = 0; i < 4; ++i) af[i]  = *(const short8*)&Msh[(i * 16 + r16) * 72 + kk + q * 8];
#pragma unroll
    for (int j = 0; j < 4; ++j) bfr[j] = *(const short8*)&XdT[(j * 16 + r16) * 72 + kk + q * 8];
#pragma unroll
    for (int i = 0; i < 4; ++i)
#pragma unroll
      for (int j = 0; j < 4; ++j)
        acc[i][j] = __builtin_amdgcn_mfma_f32_16x16x32_bf16(af[i], bfr[j], acc[i][j], 0, 0, 0);
  }
  // Y_inter = (e^{E_t} C) @ Hin^T   (t x p)
  float ei[4];
#pragma unroll
  for (int i = 0; i < 4; ++i) ei[i] = __expf(Esh[i * 16 + r16]);
  const bf16* hinp = HinB + (size_t)(bh * NCHUNK + c) * 4096;
#pragma unroll
  for (int kk = 0; kk < 64; kk += 32) {
    short8 af[4], bfr[4];
#pragma unroll
    for (int i = 0; i < 4; ++i) {
      short8 cv = *(const short8*)(Cbb + (size_t)(row0 + i * 16 + r16) * DSTATE + kk + q * 8);
#pragma unroll
      for (int jj = 0; jj < 8; ++jj) af[i][jj] = f2s(ei[i] * s2f(cv[jj]));
    }
#pragma unroll
    for (int j = 0; j < 4; ++j)
      bfr[j] = *(const short8*)(hinp + (j * 16 + r16) * 64 + kk + q * 8);
#pragma unroll
    for (int i = 0; i < 4; ++i)
#pragma unroll
      for (int j = 0; j < 4; ++j)
        acc[i][j] = __builtin_amdgcn_mfma_f32_16x16x32_bf16(af[i], bfr[j], acc[i][j], 0, 0, 0);
  }
  // epilogue: + D * x, store bf16
#pragma unroll
  for (int i = 0; i < 4; ++i)
#pragma unroll
    for (int j = 0; j < 4; ++j)
#pragma unroll
      for (int r = 0; r < 4; ++r) {
        int t = i * 16 + q * 4 + r;
        int p = j * 16 + r16;
        int g = row0 + t;
        float y = acc[i][j][r] + Dh * b2f(xbc[(size_t)g * CONVDIM + h * 64 + p]);
        yout[(size_t)g * DINNER + h * 64 + p] = f2b(y);
      }
}

// ---------------- gate (y * silu(z)) + RMSNorm ----------------
__global__ void gate_rms_kernel(const bf16* __restrict__ y, const bf16* __restrict__ zx,
                                const float* __restrict__ nw, bf16* __restrict__ yn)
{
  int row = blockIdx.x, tid = threadIdx.x;
  float v[8]; float ss = 0.f, dummy = 0.f;
#pragma unroll
  for (int k = 0; k < 8; ++k) {
    int c = k * 256 + tid;
    float z = b2f(zx[(size_t)row * DINPROJ + c]);
    float g = z / (1.f + __expf(-z));
    float val = b2f(y[(size_t)row * DINNER + c]) * g;
    v[k] = val; ss += val * val;
  }
  block_reduce_2(ss, dummy);
  float rs = rsqrtf(ss * (1.f / DINNER) + 1e-5f);
#pragma unroll
  for (int k = 0; k < 8; ++k) {
    int c = k * 256 + tid;
    yn[(size_t)row * DINNER + c] = f2b(v[k] * rs * nw[c]);
  }
}

extern "C" void kernel_launch(void* const* d_in, const int* in_sizes, int n_in,
                              void* d_out, int out_size, void* d_ws, size_t ws_size,
                              hipStream_t stream)
{
  const float* x         = (const float*)d_in[0];
  const float* ln1_w     = (const float*)d_in[1];
  const float* ln1_b     = (const float*)d_in[2];
  const float* in_proj_w = (const float*)d_in[3];
  const float* conv_w    = (const float*)d_in[4];
  const float* conv_b    = (const float*)d_in[5];
  const float* dt_bias   = (const float*)d_in[6];
  const float* A_log     = (const float*)d_in[7];
  const float* Dp        = (const float*)d_in[8];
  const float* norm_w    = (const float*)d_in[9];
  const float* out_proj_w= (const float*)d_in[10];
  const float* ln2_w     = (const float*)d_in[11];
  const float* ln2_b     = (const float*)d_in[12];
  const float* mlp_w1    = (const float*)d_in[13];
  const float* mlp_b1    = (const float*)d_in[14];
  const float* mlp_w2    = (const float*)d_in[15];
  const float* mlp_b2    = (const float*)d_in[16];

  char* ws = (char*)d_ws;
  bf16*  zx   = (bf16*)(ws + 0);            // 34,865,152
  bf16*  h1   = (bf16*)(ws + 34865152);     //  8,388,608
  bf16*  xbc  = (bf16*)(ws + 43253760);     // 17,825,792 (reused as w2b)
  bf16*  Bb   = (bf16*)(ws + 61079552);     //    524,288
  bf16*  Cbb  = (bf16*)(ws + 61603840);     //    524,288
  float* dtb  = (float*)(ws + 62128128);    //    524,288
  float* Pbuf = (float*)(ws + 62652416);    //      8,192
  float* Sbuf = (float*)(ws + 62660608);    // 33,554,432 fp32 (dead after combine)
  bf16*  yw   = (bf16*)(ws + 62660608);     // 16,777,216 bf16 (alias Sbuf lower half; Sbuf dead)
  bf16*  x2   = (bf16*)(ws + 79437824);     //  8,388,608 bf16 (alias Sbuf upper; yw-disjoint)
  bf16*  HinB = (bf16*)(ws + 96215040);     //  8,388,608
  bf16*  yn   = (bf16*)(ws + 96215040);     // 16,777,216 (overlays HinB; HinB dead after y_kernel)
  bf16*  wip  = (bf16*)(ws + 112992256);    //  8,716,288 (reused as w1b)
  bf16*  wop  = (bf16*)(ws + 121708544);    //  4,194,304 -> end 125,902,848
  bf16*  h2n  = h1;
  bf16*  mid  = zx;
  bf16*  w1b  = wip;
  bf16*  w2b  = xbc;

  // 0a. convert in_proj_w to bf16
  cvt_kernel<<<(4256 * 1024 / 4 + 255) / 256, 256, 0, stream>>>(in_proj_w, wip, 4256 * 1024 / 4);
  // 1. LN1
  ln_kernel<float><<<ROWS, 256, 0, stream>>>(x, ln1_w, ln1_b, h1);
  // 2. in_proj
  gemm_bt<0><<<dim3(34, 32), 256, 0, stream>>>(h1, wip, nullptr, nullptr, zx,
                                               ROWS, DINPROJ, DMODEL);
  // 0b. convert mlp_w1 (into wip region) and out_proj_w
  cvt_kernel<<<(4096 * 1024 / 4 + 255) / 256, 256, 0, stream>>>(mlp_w1, w1b, 4096 * 1024 / 4);
  cvt_kernel<<<(1024 * 2048 / 4 + 255) / 256, 256, 0, stream>>>(out_proj_w, wop, 1024 * 2048 / 4);
  // 3. conv + SiLU + softplus(dt)
  conv_kernel<<<ROWS, 256, 0, stream>>>(zx, conv_w, conv_b, dt_bias, xbc, Bb, Cbb, dtb);
  // 4a. SSD phase A: per-chunk end states
  chunk_state_kernel<<<2048, 64, 0, stream>>>(xbc, Bb, dtb, A_log, Sbuf, Pbuf);
  // 4b. SSD phase B: combine chunk states
  combine_kernel<<<256, 64, 0, stream>>>(Sbuf, Pbuf, HinB);
  // 4c. SSD phase C: outputs (bf16)
  y_kernel<<<2048, 64, 0, stream>>>(xbc, Bb, Cbb, dtb, HinB, A_log, Dp, yw);
  // 0c. convert mlp_w2 (xbc region dead now)
  cvt_kernel<<<(1024 * 4096 / 4 + 255) / 256, 256, 0, stream>>>(mlp_w2, w2b, 1024 * 4096 / 4);
  // 5. gate + RMSNorm
  gate_rms_kernel<<<ROWS, 256, 0, stream>>>(yw, zx, norm_w, yn);
  // 6. out_proj + residual(x, fp32) -> x2 (bf16)
  gemm_bt<2><<<dim3(8, 32), 256, 0, stream>>>(yn, wop, nullptr, x, (void*)x2,
                                              ROWS, DMODEL, DINNER);
  // 7. LN2 (bf16 in)
  ln_kernel<bf16><<<ROWS, 256, 0, stream>>>(x2, ln2_w, ln2_b, h2n);
  // 8. mlp1 + bias + GELU
  gemm_bt<1><<<dim3(32, 32), 256, 0, stream>>>(h2n, w1b, mlp_b1, nullptr, mid,
                                               ROWS, 4 * DMODEL, DMODEL);
  // 9. mlp2 + bias + residual(x2, bf16) -> out (fp32)
  gemm_bt<3><<<dim3(8, 32), 256, 0, stream>>>(mid, w2b, mlp_b2, x2, d_out,
                                              ROWS, DMODEL, 4 * DMODEL);
}

// Round 5
// 482.501 us; speedup vs baseline: 1.1273x; 1.1273x over previous
//
#include <hip/hip_runtime.h>
#include <hip/hip_bf16.h>
#include <math.h>

using bf16 = __hip_bfloat16;
typedef __attribute__((ext_vector_type(8))) short short8;
typedef __attribute__((ext_vector_type(4))) float floatx4;

#define SEQLEN   2048
#define ROWS     4096      // B*L
#define DMODEL   1024
#define DINNER   2048
#define NHEADS   32
#define HEADDIM  64
#define DSTATE   64
#define CONVDIM  2176
#define DINPROJ  4256
#define NCHUNK   32        // 2048 / 64

__device__ __forceinline__ float b2f(bf16 x) { return __bfloat162float(x); }
__device__ __forceinline__ bf16  f2b(float x) { return __float2bfloat16(x); }
__device__ __forceinline__ float s2f(short s) { union { short s; bf16 b; } u; u.s = s; return b2f(u.b); }
__device__ __forceinline__ short f2s(float f) { union { short s; bf16 b; } u; u.b = f2b(f); return u.s; }
__device__ __forceinline__ float tof(float x) { return x; }
__device__ __forceinline__ float tof(bf16 x)  { return __bfloat162float(x); }

// ---------------- async global->LDS (16B per lane) ----------------
typedef __attribute__((address_space(1))) void v_as1;
typedef __attribute__((address_space(3))) void v_as3;
__device__ __forceinline__ void gload_lds16(const void* g, void* l) {
  __builtin_amdgcn_global_load_lds((v_as1*)(g), (v_as3*)(l), 16, 0, 0);
}

// ---------------- fp32 -> bf16 conversion (4 elems/thread) ----------------
__global__ void cvt_kernel(const float* __restrict__ in, bf16* __restrict__ out, int n4) {
  int i = blockIdx.x * 256 + threadIdx.x;
  if (i < n4) {
    float4 v = ((const float4*)in)[i];
    union { bf16 h[4]; uint2 u; } r;
    r.h[0] = f2b(v.x); r.h[1] = f2b(v.y); r.h[2] = f2b(v.z); r.h[3] = f2b(v.w);
    ((uint2*)out)[i] = r.u;
  }
}

// ---------------- block reduction (2 values, 256 threads) ----------------
__device__ __forceinline__ void block_reduce_2(float& a, float& b) {
#pragma unroll
  for (int off = 32; off > 0; off >>= 1) {
    a += __shfl_xor(a, off);
    b += __shfl_xor(b, off);
  }
  __shared__ float ra[4], rb[4];
  int w = threadIdx.x >> 6;
  if ((threadIdx.x & 63) == 0) { ra[w] = a; rb[w] = b; }
  __syncthreads();
  a = ra[0] + ra[1] + ra[2] + ra[3];
  b = rb[0] + rb[1] + rb[2] + rb[3];
}

// ---------------- LayerNorm (1024 cols, fp32/bf16 in, bf16 out) ----------------
template<typename TIN>
__global__ void ln_kernel(const TIN* __restrict__ x, const float* __restrict__ w,
                          const float* __restrict__ b, bf16* __restrict__ out)
{
  int row = blockIdx.x;
  int tid = threadIdx.x;
  float v[4]; float s = 0.f, sq = 0.f;
#pragma unroll
  for (int k = 0; k < 4; ++k) {
    int c = k * 256 + tid;
    float xv = tof(x[(size_t)row * DMODEL + c]);
    v[k] = xv; s += xv; sq += xv * xv;
  }
  block_reduce_2(s, sq);
  float mu  = s * (1.f / DMODEL);
  float var = sq * (1.f / DMODEL) - mu * mu;
  float rs  = rsqrtf(var + 1e-5f);
#pragma unroll
  for (int k = 0; k < 4; ++k) {
    int c = k * 256 + tid;
    out[(size_t)row * DMODEL + c] = f2b((v[k] - mu) * rs * w[c] + b[c]);
  }
}

// ---------------- epilogue helper ----------------
// EPI 0: store bf16
// EPI 1: +bias(fp32), exact GELU, store bf16
// EPI 2: +resid(fp32), store bf16
// EPI 3: +bias(fp32) +resid(bf16), store fp32
template<int EPI>
__device__ __forceinline__ void epi_store(float v, size_t off, int col,
                                          const float* bias, const void* resid, void* Cout)
{
  if (EPI == 0) {
    ((bf16*)Cout)[off] = f2b(v);
  } else if (EPI == 1) {
    v += bias[col];
    v = 0.5f * v * (1.f + erff(v * 0.70710678118654752f));
    ((bf16*)Cout)[off] = f2b(v);
  } else if (EPI == 2) {
    v += ((const float*)resid)[off];
    ((bf16*)Cout)[off] = f2b(v);
  } else {
    v += bias[col] + b2f(((const bf16*)resid)[off]);
    ((float*)Cout)[off] = v;
  }
}

// ---------------- GEMM 128x128 tile (single-buffer, r3-verified) ----------------
template<int EPI>
__global__ __launch_bounds__(256, 2)
void gemm_bt(const bf16* __restrict__ A, const bf16* __restrict__ W,
             const float* __restrict__ bias, const void* __restrict__ resid,
             void* __restrict__ Cout, int M, int N, int K)
{
  __shared__ __align__(16) short Asl[128 * 64];
  __shared__ __align__(16) short Bsl[128 * 64];
  const int tid  = threadIdx.x;
  const int lane = tid & 63;
  const int wv   = tid >> 6;
  const int wm   = wv >> 1, wn = wv & 1;
  const int r16  = lane & 15, q = lane >> 4;
  const int m0   = blockIdx.y * 128;
  const int n0   = blockIdx.x * 128;

  floatx4 acc[4][4] = {};

  for (int k0 = 0; k0 < K; k0 += 64) {
#pragma unroll
    for (int it = 0; it < 4; ++it) {
      int idx = it * 256 + tid;
      int row = m0 + (idx >> 3);
      int cb  = (idx & 7) << 3;
      gload_lds16(A + (size_t)row * K + k0 + cb, &Asl[idx * 8]);
    }
#pragma unroll
    for (int it = 0; it < 4; ++it) {
      int idx = it * 256 + tid;
      int row = n0 + (idx >> 3);
      if (row > N - 1) row = N - 1;
      int cb  = (idx & 7) << 3;
      gload_lds16(W + (size_t)row * K + k0 + cb, &Bsl[idx * 8]);
    }
    __syncthreads();
#pragma unroll
    for (int kk = 0; kk < 64; kk += 32) {
      short8 af[4], bfr[4];
#pragma unroll
      for (int i = 0; i < 4; ++i)
        af[i] = *(const short8*)&Asl[(wm * 64 + i * 16 + r16) * 64 + kk + q * 8];
#pragma unroll
      for (int j = 0; j < 4; ++j)
        bfr[j] = *(const short8*)&Bsl[(wn * 64 + j * 16 + r16) * 64 + kk + q * 8];
#pragma unroll
      for (int i = 0; i < 4; ++i)
#pragma unroll
        for (int j = 0; j < 4; ++j)
          acc[i][j] = __builtin_amdgcn_mfma_f32_16x16x32_bf16(af[i], bfr[j], acc[i][j], 0, 0, 0);
    }
    __syncthreads();
  }

#pragma unroll
  for (int i = 0; i < 4; ++i)
#pragma unroll
    for (int j = 0; j < 4; ++j)
#pragma unroll
      for (int r = 0; r < 4; ++r) {
        int row = m0 + wm * 64 + i * 16 + q * 4 + r;
        int col = n0 + wn * 64 + j * 16 + r16;
        if (col < N)
          epi_store<EPI>(acc[i][j][r], (size_t)row * N + col, col, bias, resid, Cout);
      }
}

// ---------------- GEMM 64x128 tile: for N=1024 (doubles blocks -> 2/CU) ----------------
template<int EPI>
__global__ __launch_bounds__(256, 2)
void gemm_bt_64(const bf16* __restrict__ A, const bf16* __restrict__ W,
                const float* __restrict__ bias, const void* __restrict__ resid,
                void* __restrict__ Cout, int M, int N, int K)
{
  __shared__ __align__(16) short Asl[64 * 64];    //  8 KB
  __shared__ __align__(16) short Bsl[128 * 64];   // 16 KB
  const int tid  = threadIdx.x;
  const int lane = tid & 63;
  const int wv   = tid >> 6;                      // wave covers cols wv*32
  const int r16  = lane & 15, q = lane >> 4;
  const int m0   = blockIdx.y * 64;
  const int n0   = blockIdx.x * 128;

  floatx4 acc[4][2] = {};

  for (int k0 = 0; k0 < K; k0 += 64) {
#pragma unroll
    for (int it = 0; it < 2; ++it) {
      int idx = it * 256 + tid;
      int row = m0 + (idx >> 3);
      int cb  = (idx & 7) << 3;
      gload_lds16(A + (size_t)row * K + k0 + cb, &Asl[idx * 8]);
    }
#pragma unroll
    for (int it = 0; it < 4; ++it) {
      int idx = it * 256 + tid;
      int row = n0 + (idx >> 3);
      int cb  = (idx & 7) << 3;
      gload_lds16(W + (size_t)row * K + k0 + cb, &Bsl[idx * 8]);
    }
    __syncthreads();
#pragma unroll
    for (int kk = 0; kk < 64; kk += 32) {
      short8 af[4], bfr[2];
#pragma unroll
      for (int i = 0; i < 4; ++i)
        af[i] = *(const short8*)&Asl[(i * 16 + r16) * 64 + kk + q * 8];
#pragma unroll
      for (int j = 0; j < 2; ++j)
        bfr[j] = *(const short8*)&Bsl[(wv * 32 + j * 16 + r16) * 64 + kk + q * 8];
#pragma unroll
      for (int i = 0; i < 4; ++i)
#pragma unroll
        for (int j = 0; j < 2; ++j)
          acc[i][j] = __builtin_amdgcn_mfma_f32_16x16x32_bf16(af[i], bfr[j], acc[i][j], 0, 0, 0);
    }
    __syncthreads();
  }

#pragma unroll
  for (int i = 0; i < 4; ++i)
#pragma unroll
    for (int j = 0; j < 2; ++j)
#pragma unroll
      for (int r = 0; r < 4; ++r) {
        int row = m0 + i * 16 + q * 4 + r;
        int col = n0 + wv * 32 + j * 16 + r16;
        epi_store<EPI>(acc[i][j][r], (size_t)row * N + col, col, bias, resid, Cout);
      }
}

// ---------------- depthwise causal conv (4 tap) + SiLU + softplus(dt) ----------------
__global__ void conv_kernel(const bf16* __restrict__ zx, const float* __restrict__ cw,
                            const float* __restrict__ cb, const float* __restrict__ dtbias,
                            bf16* __restrict__ xbc, bf16* __restrict__ Bb,
                            bf16* __restrict__ Cbb, float* __restrict__ dtb)
{
  int row = blockIdx.x;
  int b = row >> 11, t = row & 2047;
  for (int c = threadIdx.x; c < CONVDIM; c += 256) {
    float acc = cb[c];
#pragma unroll
    for (int k = 0; k < 4; ++k) {
      int tt = t + k - 3;
      if (tt >= 0)
        acc += b2f(zx[((size_t)(b * SEQLEN + tt)) * DINPROJ + DINNER + c]) * cw[c * 4 + k];
    }
    float s = acc / (1.f + __expf(-acc));   // SiLU
    xbc[(size_t)row * CONVDIM + c] = f2b(s);
    if (c >= DINNER) {
      if (c < DINNER + DSTATE) Bb[row * DSTATE + (c - DINNER)] = f2b(s);
      else                     Cbb[row * DSTATE + (c - DINNER - DSTATE)] = f2b(s);
    }
  }
  if (threadIdx.x < NHEADS) {
    int hh = threadIdx.x;
    float raw = b2f(zx[(size_t)row * DINPROJ + DINNER + CONVDIM + hh]) + dtbias[hh];
    float dt = raw > 20.f ? raw : log1pf(__expf(raw));   // softplus
    dtb[row * NHEADS + hh] = dt;
  }
}

// ---------------- wave inclusive prefix sum helper ----------------
__device__ __forceinline__ float wave_incl_prefix(float a, int lane) {
#pragma unroll
  for (int off = 1; off < 64; off <<= 1) {
    float o = __shfl_up(a, off);
    if (lane >= off) a += o;
  }
  return a;
}

// ---------------- SSD phase A: chunk end-state S = Xw^T @ B, decay P ----------------
__global__ __launch_bounds__(64)
void chunk_state_kernel(const bf16* __restrict__ xbc, const bf16* __restrict__ Bb,
                        const float* __restrict__ dtb, const float* __restrict__ A_log,
                        float* __restrict__ Sbuf, float* __restrict__ Pbuf)
{
  const int blk = blockIdx.x;
  const int c = blk & 31, h = (blk >> 5) & 31, b = blk >> 10;
  const int bh = b * 32 + h;
  const int lane = threadIdx.x;              // = s (timestep within chunk)
  const int row = b * SEQLEN + c * 64 + lane;
  const float Ah = -__expf(A_log[h]);

  float dts = dtb[row * NHEADS + h];
  float E = wave_incl_prefix(dts * Ah, lane);
  float EQ = __shfl(E, 63);
  float w = __expf(EQ - E) * dts;
  if (lane == 63) Pbuf[bh * NCHUNK + c] = __expf(EQ);

  __shared__ __align__(16) short XwT[64 * 72];   // [p][s] pad 72
  __shared__ __align__(16) short BT[64 * 72];    // [n][s] pad 72

  const bf16* xrow = xbc + (size_t)row * CONVDIM + h * 64;
  const bf16* brow = Bb + (size_t)row * DSTATE;
#pragma unroll
  for (int i = 0; i < 8; ++i) {
    short8 xv = *(const short8*)(xrow + i * 8);
    short8 bv = *(const short8*)(brow + i * 8);
#pragma unroll
    for (int j = 0; j < 8; ++j) {
      XwT[(i * 8 + j) * 72 + lane] = f2s(w * s2f(xv[j]));
      BT[(i * 8 + j) * 72 + lane]  = bv[j];
    }
  }
  __syncthreads();

  const int r16 = lane & 15, q = lane >> 4;
  floatx4 acc[4][4] = {};
#pragma unroll
  for (int kk = 0; kk < 64; kk += 32) {
    short8 af[4], bfr[4];
#pragma unroll
    for (int i = 0; i < 4; ++i) af[i]  = *(const short8*)&XwT[(i * 16 + r16) * 72 + kk + q * 8];
#pragma unroll
    for (int j = 0; j < 4; ++j) bfr[j] = *(const short8*)&BT[(j * 16 + r16) * 72 + kk + q * 8];
#pragma unroll
    for (int i = 0; i < 4; ++i)
#pragma unroll
      for (int j = 0; j < 4; ++j)
        acc[i][j] = __builtin_amdgcn_mfma_f32_16x16x32_bf16(af[i], bfr[j], acc[i][j], 0, 0, 0);
  }
  float* Sout = Sbuf + (size_t)(bh * NCHUNK + c) * 4096;
#pragma unroll
  for (int i = 0; i < 4; ++i)
#pragma unroll
    for (int j = 0; j < 4; ++j)
#pragma unroll
      for (int r = 0; r < 4; ++r)
        Sout[(i * 16 + q * 4 + r) * 64 + (j * 16 + r16)] = acc[i][j][r];
}

// ---------------- SSD phase B: serial chunk combine (scalar decay) ----------------
__global__ __launch_bounds__(64)
void combine_kernel(const float* __restrict__ Sbuf, const float* __restrict__ Pbuf,
                    bf16* __restrict__ HinB)
{
  const int bh = blockIdx.x >> 2, slab = blockIdx.x & 3;
  const int base = slab * 1024 + threadIdx.x * 16;
  float h[16];
#pragma unroll
  for (int k = 0; k < 16; ++k) h[k] = 0.f;
  for (int c = 0; c < NCHUNK; ++c) {
    size_t off = (size_t)(bh * NCHUNK + c) * 4096 + base;
    union { short s[16]; uint4 q[2]; } pk;
#pragma unroll
    for (int k = 0; k < 16; ++k) pk.s[k] = f2s(h[k]);
    *(uint4*)(HinB + off)     = pk.q[0];
    *(uint4*)(HinB + off + 8) = pk.q[1];
    float P = Pbuf[bh * NCHUNK + c];
    const float4* S4 = (const float4*)(Sbuf + off);
#pragma unroll
    for (int k = 0; k < 4; ++k) {
      float4 s = S4[k];
      h[k*4+0] = h[k*4+0] * P + s.x;
      h[k*4+1] = h[k*4+1] * P + s.y;
      h[k*4+2] = h[k*4+2] * P + s.z;
      h[k*4+3] = h[k*4+3] * P + s.w;
    }
  }
}

// ---------------- SSD phase C: Y = (mask ⊙ C B^T) @ Xdt + (e^E C) @ Hin^T + D x ----------------
__global__ __launch_bounds__(64)
void y_kernel(const bf16* __restrict__ xbc, const bf16* __restrict__ Bb,
              const bf16* __restrict__ Cbb, const float* __restrict__ dtb,
              const bf16* __restrict__ HinB, const float* __restrict__ A_log,
              const float* __restrict__ Dp, bf16* __restrict__ yout)
{
  const int blk = blockIdx.x;
  const int c = blk & 31, h = (blk >> 5) & 31, b = blk >> 10;
  const int bh = b * 32 + h;
  const int lane = threadIdx.x;              // = s for the builds
  const int row0 = b * SEQLEN + c * 64;
  const int row = row0 + lane;
  const float Ah = -__expf(A_log[h]);
  const float Dh = Dp[h];

  __shared__ __align__(16) short XdT[64 * 72];  // [p][s]
  __shared__ __align__(16) short Msh[64 * 72];  // [t][s]
  __shared__ float Esh[64];

  float dts = dtb[row * NHEADS + h];
  float E = wave_incl_prefix(dts * Ah, lane);
  Esh[lane] = E;

  const bf16* xrow = xbc + (size_t)row * CONVDIM + h * 64;
#pragma unroll
  for (int i = 0; i < 8; ++i) {
    short8 xv = *(const short8*)(xrow + i * 8);
#pragma unroll
    for (int j = 0; j < 8; ++j)
      XdT[(i * 8 + j) * 72 + lane] = f2s(dts * s2f(xv[j]));
  }
  __syncthreads();

  const int r16 = lane & 15, q = lane >> 4;

  // G = C @ B^T  (t x s)
  floatx4 accg[4][4] = {};
#pragma unroll
  for (int kk = 0; kk < 64; kk += 32) {
    short8 af[4], bfr[4];
#pragma unroll
    for (int i = 0; i < 4; ++i)
      af[i]  = *(const short8*)(Cbb + (size_t)(row0 + i * 16 + r16) * DSTATE + kk + q * 8);
#pragma unroll
    for (int j = 0; j < 4; ++j)
      bfr[j] = *(const short8*)(Bb + (size_t)(row0 + j * 16 + r16) * DSTATE + kk + q * 8);
#pragma unroll
    for (int i = 0; i < 4; ++i)
#pragma unroll
      for (int j = 0; j < 4; ++j)
        accg[i][j] = __builtin_amdgcn_mfma_f32_16x16x32_bf16(af[i], bfr[j], accg[i][j], 0, 0, 0);
  }
  // causal decay mask -> Msh (bf16, A-operand layout for next MFMA)
#pragma unroll
  for (int i = 0; i < 4; ++i)
#pragma unroll
    for (int j = 0; j < 4; ++j)
#pragma unroll
      for (int r = 0; r < 4; ++r) {
        int t = i * 16 + q * 4 + r;
        int s = j * 16 + r16;
        float v = (s <= t) ? __expf(Esh[t] - Esh[s]) * accg[i][j][r] : 0.f;
        Msh[t * 72 + s] = f2s(v);
      }
  __syncthreads();

  floatx4 acc[4][4] = {};
  // Y_intra = M @ Xdt   (t x p)
#pragma unroll
  for (int kk = 0; kk < 64; kk += 32) {
    short8 af[4], bfr[4];
#pragma unroll
    for (int i = 0; i < 4; ++i) af[i]  = *(const short8*)&Msh[(i * 16 + r16) * 72 + kk + q * 8];
#pragma unroll
    for (int j = 0; j < 4; ++j) bfr[j] = *(const short8*)&XdT[(j * 16 + r16) * 72 + kk + q * 8];
#pragma unroll
    for (int i = 0; i < 4; ++i)
#pragma unroll
      for (int j = 0; j < 4; ++j)
        acc[i][j] = __builtin_amdgcn_mfma_f32_16x16x32_bf16(af[i], bfr[j], acc[i][j], 0, 0, 0);
  }
  // Y_inter = (e^{E_t} C) @ Hin^T   (t x p)
  float ei[4];
#pragma unroll
  for (int i = 0; i < 4; ++i) ei[i] = __expf(Esh[i * 16 + r16]);
  const bf16* hinp = HinB + (size_t)(bh * NCHUNK + c) * 4096;
#pragma unroll
  for (int kk = 0; kk < 64; kk += 32) {
    short8 af[4], bfr[4];
#pragma unroll
    for (int i = 0; i < 4; ++i) {
      short8 cv = *(const short8*)(Cbb + (size_t)(row0 + i * 16 + r16) * DSTATE + kk + q * 8);
#pragma unroll
      for (int jj = 0; jj < 8; ++jj) af[i][jj] = f2s(ei[i] * s2f(cv[jj]));
    }
#pragma unroll
    for (int j = 0; j < 4; ++j)
      bfr[j] = *(const short8*)(hinp + (j * 16 + r16) * 64 + kk + q * 8);
#pragma unroll
    for (int i = 0; i < 4; ++i)
#pragma unroll
      for (int j = 0; j < 4; ++j)
        acc[i][j] = __builtin_amdgcn_mfma_f32_16x16x32_bf16(af[i], bfr[j], acc[i][j], 0, 0, 0);
  }
  // epilogue: + D * x, store bf16
#pragma unroll
  for (int i = 0; i < 4; ++i)
#pragma unroll
    for (int j = 0; j < 4; ++j)
#pragma unroll
      for (int r = 0; r < 4; ++r) {
        int t = i * 16 + q * 4 + r;
        int p = j * 16 + r16;
        int g = row0 + t;
        float y = acc[i][j][r] + Dh * b2f(xbc[(size_t)g * CONVDIM + h * 64 + p]);
        yout[(size_t)g * DINNER + h * 64 + p] = f2b(y);
      }
}

// ---------------- gate (y * silu(z)) + RMSNorm ----------------
__global__ void gate_rms_kernel(const bf16* __restrict__ y, const bf16* __restrict__ zx,
                                const float* __restrict__ nw, bf16* __restrict__ yn)
{
  int row = blockIdx.x, tid = threadIdx.x;
  float v[8]; float ss = 0.f, dummy = 0.f;
#pragma unroll
  for (int k = 0; k < 8; ++k) {
    int c = k * 256 + tid;
    float z = b2f(zx[(size_t)row * DINPROJ + c]);
    float g = z / (1.f + __expf(-z));
    float val = b2f(y[(size_t)row * DINNER + c]) * g;
    v[k] = val; ss += val * val;
  }
  block_reduce_2(ss, dummy);
  float rs = rsqrtf(ss * (1.f / DINNER) + 1e-5f);
#pragma unroll
  for (int k = 0; k < 8; ++k) {
    int c = k * 256 + tid;
    yn[(size_t)row * DINNER + c] = f2b(v[k] * rs * nw[c]);
  }
}

extern "C" void kernel_launch(void* const* d_in, const int* in_sizes, int n_in,
                              void* d_out, int out_size, void* d_ws, size_t ws_size,
                              hipStream_t stream)
{
  const float* x         = (const float*)d_in[0];
  const float* ln1_w     = (const float*)d_in[1];
  const float* ln1_b     = (const float*)d_in[2];
  const float* in_proj_w = (const float*)d_in[3];
  const float* conv_w    = (const float*)d_in[4];
  const float* conv_b    = (const float*)d_in[5];
  const float* dt_bias   = (const float*)d_in[6];
  const float* A_log     = (const float*)d_in[7];
  const float* Dp        = (const float*)d_in[8];
  const float* norm_w    = (const float*)d_in[9];
  const float* out_proj_w= (const float*)d_in[10];
  const float* ln2_w     = (const float*)d_in[11];
  const float* ln2_b     = (const float*)d_in[12];
  const float* mlp_w1    = (const float*)d_in[13];
  const float* mlp_b1    = (const float*)d_in[14];
  const float* mlp_w2    = (const float*)d_in[15];
  const float* mlp_b2    = (const float*)d_in[16];

  char* ws = (char*)d_ws;
  bf16*  zx   = (bf16*)(ws + 0);            // 34,865,152
  bf16*  h1   = (bf16*)(ws + 34865152);     //  8,388,608
  bf16*  xbc  = (bf16*)(ws + 43253760);     // 17,825,792 (reused as w2b)
  bf16*  Bb   = (bf16*)(ws + 61079552);     //    524,288
  bf16*  Cbb  = (bf16*)(ws + 61603840);     //    524,288
  float* dtb  = (float*)(ws + 62128128);    //    524,288
  float* Pbuf = (float*)(ws + 62652416);    //      8,192
  float* Sbuf = (float*)(ws + 62660608);    // 33,554,432 fp32 (dead after combine)
  bf16*  yw   = (bf16*)(ws + 62660608);     // 16,777,216 bf16 (alias Sbuf lower; Sbuf dead)
  bf16*  x2   = (bf16*)(ws + 79437824);     //  8,388,608 bf16 (alias Sbuf upper; yw-disjoint)
  bf16*  HinB = (bf16*)(ws + 96215040);     //  8,388,608
  bf16*  yn   = (bf16*)(ws + 96215040);     // 16,777,216 (overlays HinB; HinB dead after y_kernel)
  bf16*  wip  = (bf16*)(ws + 112992256);    //  8,716,288 (reused as w1b)
  bf16*  wop  = (bf16*)(ws + 121708544);    //  4,194,304 -> end 125,902,848
  bf16*  h2n  = h1;
  bf16*  mid  = zx;
  bf16*  w1b  = wip;
  bf16*  w2b  = xbc;

  // 0a. convert in_proj_w to bf16
  cvt_kernel<<<(4256 * 1024 / 4 + 255) / 256, 256, 0, stream>>>(in_proj_w, wip, 4256 * 1024 / 4);
  // 1. LN1
  ln_kernel<float><<<ROWS, 256, 0, stream>>>(x, ln1_w, ln1_b, h1);
  // 2. in_proj
  gemm_bt<0><<<dim3(34, 32), 256, 0, stream>>>(h1, wip, nullptr, nullptr, zx,
                                               ROWS, DINPROJ, DMODEL);
  // 0b. convert mlp_w1 (into wip region) and out_proj_w
  cvt_kernel<<<(4096 * 1024 / 4 + 255) / 256, 256, 0, stream>>>(mlp_w1, w1b, 4096 * 1024 / 4);
  cvt_kernel<<<(1024 * 2048 / 4 + 255) / 256, 256, 0, stream>>>(out_proj_w, wop, 1024 * 2048 / 4);
  // 3. conv + SiLU + softplus(dt)
  conv_kernel<<<ROWS, 256, 0, stream>>>(zx, conv_w, conv_b, dt_bias, xbc, Bb, Cbb, dtb);
  // 4a. SSD phase A: per-chunk end states
  chunk_state_kernel<<<2048, 64, 0, stream>>>(xbc, Bb, dtb, A_log, Sbuf, Pbuf);
  // 4b. SSD phase B: combine chunk states
  combine_kernel<<<256, 64, 0, stream>>>(Sbuf, Pbuf, HinB);
  // 4c. SSD phase C: outputs (bf16)
  y_kernel<<<2048, 64, 0, stream>>>(xbc, Bb, Cbb, dtb, HinB, A_log, Dp, yw);
  // 0c. convert mlp_w2 (xbc region dead now)
  cvt_kernel<<<(1024 * 4096 / 4 + 255) / 256, 256, 0, stream>>>(mlp_w2, w2b, 1024 * 4096 / 4);
  // 5. gate + RMSNorm
  gate_rms_kernel<<<ROWS, 256, 0, stream>>>(yw, zx, norm_w, yn);
  // 6. out_proj + residual(x, fp32) -> x2 (bf16)   [64x128 tile, 512 blocks]
  gemm_bt_64<2><<<dim3(8, 64), 256, 0, stream>>>(yn, wop, nullptr, x, (void*)x2,
                                                 ROWS, DMODEL, DINNER);
  // 7. LN2 (bf16 in)
  ln_kernel<bf16><<<ROWS, 256, 0, stream>>>(x2, ln2_w, ln2_b, h2n);
  // 8. mlp1 + bias + GELU
  gemm_bt<1><<<dim3(32, 32), 256, 0, stream>>>(h2n, w1b, mlp_b1, nullptr, mid,
                                               ROWS, 4 * DMODEL, DMODEL);
  // 9. mlp2 + bias + residual(x2, bf16) -> out (fp32)   [64x128 tile, 512 blocks]
  gemm_bt_64<3><<<dim3(8, 64), 256, 0, stream>>>(mid, w2b, mlp_b2, x2, d_out,
                                                 ROWS, DMODEL, 4 * DMODEL);
}

// Round 6
// 470.957 us; speedup vs baseline: 1.1549x; 1.0245x over previous
//
#include <hip/hip_runtime.h>
#include <hip/hip_bf16.h>
#include <math.h>

using bf16 = __hip_bfloat16;
typedef __attribute__((ext_vector_type(8))) short short8;
typedef __attribute__((ext_vector_type(4))) float floatx4;

#define SEQLEN   2048
#define ROWS     4096      // B*L
#define DMODEL   1024
#define DINNER   2048
#define NHEADS   32
#define HEADDIM  64
#define DSTATE   64
#define CONVDIM  2176
#define DINPROJ  4256
#define NCHUNK   32        // 2048 / 64

__device__ __forceinline__ float b2f(bf16 x) { return __bfloat162float(x); }
__device__ __forceinline__ bf16  f2b(float x) { return __float2bfloat16(x); }
__device__ __forceinline__ float s2f(short s) { union { short s; bf16 b; } u; u.s = s; return b2f(u.b); }
__device__ __forceinline__ short f2s(float f) { union { short s; bf16 b; } u; u.b = f2b(f); return u.s; }
__device__ __forceinline__ float tof(float x) { return x; }
__device__ __forceinline__ float tof(bf16 x)  { return __bfloat162float(x); }

// ---------------- async global->LDS (16B per lane) ----------------
typedef __attribute__((address_space(1))) void v_as1;
typedef __attribute__((address_space(3))) void v_as3;
__device__ __forceinline__ void gload_lds16(const void* g, void* l) {
  __builtin_amdgcn_global_load_lds((v_as1*)(g), (v_as3*)(l), 16, 0, 0);
}

// ---------------- fp32 -> bf16 conversion (4 elems/thread) ----------------
__global__ void cvt_kernel(const float* __restrict__ in, bf16* __restrict__ out, int n4) {
  int i = blockIdx.x * 256 + threadIdx.x;
  if (i < n4) {
    float4 v = ((const float4*)in)[i];
    union { bf16 h[4]; uint2 u; } r;
    r.h[0] = f2b(v.x); r.h[1] = f2b(v.y); r.h[2] = f2b(v.z); r.h[3] = f2b(v.w);
    ((uint2*)out)[i] = r.u;
  }
}

// ---------------- block reduction (2 values, 256 threads) ----------------
__device__ __forceinline__ void block_reduce_2(float& a, float& b) {
#pragma unroll
  for (int off = 32; off > 0; off >>= 1) {
    a += __shfl_xor(a, off);
    b += __shfl_xor(b, off);
  }
  __shared__ float ra[4], rb[4];
  int w = threadIdx.x >> 6;
  if ((threadIdx.x & 63) == 0) { ra[w] = a; rb[w] = b; }
  __syncthreads();
  a = ra[0] + ra[1] + ra[2] + ra[3];
  b = rb[0] + rb[1] + rb[2] + rb[3];
}

// ---------------- LayerNorm (1024 cols, fp32/bf16 in, bf16 out) ----------------
template<typename TIN>
__global__ void ln_kernel(const TIN* __restrict__ x, const float* __restrict__ w,
                          const float* __restrict__ b, bf16* __restrict__ out)
{
  int row = blockIdx.x;
  int tid = threadIdx.x;
  float v[4]; float s = 0.f, sq = 0.f;
#pragma unroll
  for (int k = 0; k < 4; ++k) {
    int c = k * 256 + tid;
    float xv = tof(x[(size_t)row * DMODEL + c]);
    v[k] = xv; s += xv; sq += xv * xv;
  }
  block_reduce_2(s, sq);
  float mu  = s * (1.f / DMODEL);
  float var = sq * (1.f / DMODEL) - mu * mu;
  float rs  = rsqrtf(var + 1e-5f);
#pragma unroll
  for (int k = 0; k < 4; ++k) {
    int c = k * 256 + tid;
    out[(size_t)row * DMODEL + c] = f2b((v[k] - mu) * rs * w[c] + b[c]);
  }
}

// ---------------- epilogue helper ----------------
// EPI 0: store bf16
// EPI 1: +bias(fp32), exact GELU, store bf16
// EPI 2: +resid(fp32), store bf16
// EPI 3: +bias(fp32) +resid(bf16), store fp32
template<int EPI>
__device__ __forceinline__ void epi_store(float v, size_t off, int col,
                                          const float* bias, const void* resid, void* Cout)
{
  if (EPI == 0) {
    ((bf16*)Cout)[off] = f2b(v);
  } else if (EPI == 1) {
    v += bias[col];
    v = 0.5f * v * (1.f + erff(v * 0.70710678118654752f));
    ((bf16*)Cout)[off] = f2b(v);
  } else if (EPI == 2) {
    v += ((const float*)resid)[off];
    ((bf16*)Cout)[off] = f2b(v);
  } else {
    v += bias[col] + b2f(((const bf16*)resid)[off]);
    ((float*)Cout)[off] = v;
  }
}

// ---------------- GEMM 128x128 tile; blockIdx.x = M-tile (XCD affinity on A rows) ----------------
template<int EPI>
__global__ __launch_bounds__(256, 2)
void gemm_bt(const bf16* __restrict__ A, const bf16* __restrict__ W,
             const float* __restrict__ bias, const void* __restrict__ resid,
             void* __restrict__ Cout, int M, int N, int K)
{
  __shared__ __align__(16) short Asl[128 * 64];
  __shared__ __align__(16) short Bsl[128 * 64];
  const int tid  = threadIdx.x;
  const int lane = tid & 63;
  const int wv   = tid >> 6;
  const int wm   = wv >> 1, wn = wv & 1;
  const int r16  = lane & 15, q = lane >> 4;
  const int m0   = blockIdx.x * 128;   // x = M-tile: bid%8 == m-tile%8 -> same-A-rows pin to one XCD
  const int n0   = blockIdx.y * 128;

  floatx4 acc[4][4] = {};

  for (int k0 = 0; k0 < K; k0 += 64) {
#pragma unroll
    for (int it = 0; it < 4; ++it) {
      int idx = it * 256 + tid;
      int row = m0 + (idx >> 3);
      int cb  = (idx & 7) << 3;
      gload_lds16(A + (size_t)row * K + k0 + cb, &Asl[idx * 8]);
    }
#pragma unroll
    for (int it = 0; it < 4; ++it) {
      int idx = it * 256 + tid;
      int row = n0 + (idx >> 3);
      if (row > N - 1) row = N - 1;
      int cb  = (idx & 7) << 3;
      gload_lds16(W + (size_t)row * K + k0 + cb, &Bsl[idx * 8]);
    }
    __syncthreads();
#pragma unroll
    for (int kk = 0; kk < 64; kk += 32) {
      short8 af[4], bfr[4];
#pragma unroll
      for (int i = 0; i < 4; ++i)
        af[i] = *(const short8*)&Asl[(wm * 64 + i * 16 + r16) * 64 + kk + q * 8];
#pragma unroll
      for (int j = 0; j < 4; ++j)
        bfr[j] = *(const short8*)&Bsl[(wn * 64 + j * 16 + r16) * 64 + kk + q * 8];
#pragma unroll
      for (int i = 0; i < 4; ++i)
#pragma unroll
        for (int j = 0; j < 4; ++j)
          acc[i][j] = __builtin_amdgcn_mfma_f32_16x16x32_bf16(af[i], bfr[j], acc[i][j], 0, 0, 0);
    }
    __syncthreads();
  }

#pragma unroll
  for (int i = 0; i < 4; ++i)
#pragma unroll
    for (int j = 0; j < 4; ++j)
#pragma unroll
      for (int r = 0; r < 4; ++r) {
        int row = m0 + wm * 64 + i * 16 + q * 4 + r;
        int col = n0 + wn * 64 + j * 16 + r16;
        if (col < N)
          epi_store<EPI>(acc[i][j][r], (size_t)row * N + col, col, bias, resid, Cout);
      }
}

// ---------------- GEMM 64x64 tile (N=1024 GEMMs): 1024 blocks = 4/CU, 16 KB LDS ----------------
template<int EPI>
__global__ __launch_bounds__(256, 4)
void gemm_bt_6464(const bf16* __restrict__ A, const bf16* __restrict__ W,
                  const float* __restrict__ bias, const void* __restrict__ resid,
                  void* __restrict__ Cout, int M, int N, int K)
{
  __shared__ __align__(16) short Asl[64 * 64];    // 8 KB
  __shared__ __align__(16) short Bsl[64 * 64];    // 8 KB
  const int tid  = threadIdx.x;
  const int lane = tid & 63;
  const int wv   = tid >> 6;
  const int wm   = wv >> 1, wn = wv & 1;          // 2x2 wave grid of 32x32 sub-tiles
  const int r16  = lane & 15, q = lane >> 4;
  const int m0   = blockIdx.x * 64;               // x = M-tile (64 tiles, mult of 8): XCD pin on A
  const int n0   = blockIdx.y * 64;

  floatx4 acc[2][2] = {};

  for (int k0 = 0; k0 < K; k0 += 64) {
#pragma unroll
    for (int it = 0; it < 2; ++it) {
      int idx = it * 256 + tid;
      gload_lds16(A + (size_t)(m0 + (idx >> 3)) * K + k0 + ((idx & 7) << 3), &Asl[idx * 8]);
    }
#pragma unroll
    for (int it = 0; it < 2; ++it) {
      int idx = it * 256 + tid;
      gload_lds16(W + (size_t)(n0 + (idx >> 3)) * K + k0 + ((idx & 7) << 3), &Bsl[idx * 8]);
    }
    __syncthreads();
#pragma unroll
    for (int kk = 0; kk < 64; kk += 32) {
      short8 af[2], bfr[2];
#pragma unroll
      for (int i = 0; i < 2; ++i)
        af[i] = *(const short8*)&Asl[(wm * 32 + i * 16 + r16) * 64 + kk + q * 8];
#pragma unroll
      for (int j = 0; j < 2; ++j)
        bfr[j] = *(const short8*)&Bsl[(wn * 32 + j * 16 + r16) * 64 + kk + q * 8];
#pragma unroll
      for (int i = 0; i < 2; ++i)
#pragma unroll
        for (int j = 0; j < 2; ++j)
          acc[i][j] = __builtin_amdgcn_mfma_f32_16x16x32_bf16(af[i], bfr[j], acc[i][j], 0, 0, 0);
    }
    __syncthreads();
  }

#pragma unroll
  for (int i = 0; i < 2; ++i)
#pragma unroll
    for (int j = 0; j < 2; ++j)
#pragma unroll
      for (int r = 0; r < 4; ++r) {
        int row = m0 + wm * 32 + i * 16 + q * 4 + r;
        int col = n0 + wn * 32 + j * 16 + r16;
        epi_store<EPI>(acc[i][j][r], (size_t)row * N + col, col, bias, resid, Cout);
      }
}

// ---------------- depthwise causal conv (4 tap) + SiLU + softplus(dt) ----------------
__global__ void conv_kernel(const bf16* __restrict__ zx, const float* __restrict__ cw,
                            const float* __restrict__ cb, const float* __restrict__ dtbias,
                            bf16* __restrict__ xbc, bf16* __restrict__ Bb,
                            bf16* __restrict__ Cbb, float* __restrict__ dtb)
{
  int row = blockIdx.x;
  int b = row >> 11, t = row & 2047;
  for (int c = threadIdx.x; c < CONVDIM; c += 256) {
    float acc = cb[c];
#pragma unroll
    for (int k = 0; k < 4; ++k) {
      int tt = t + k - 3;
      if (tt >= 0)
        acc += b2f(zx[((size_t)(b * SEQLEN + tt)) * DINPROJ + DINNER + c]) * cw[c * 4 + k];
    }
    float s = acc / (1.f + __expf(-acc));   // SiLU
    xbc[(size_t)row * CONVDIM + c] = f2b(s);
    if (c >= DINNER) {
      if (c < DINNER + DSTATE) Bb[row * DSTATE + (c - DINNER)] = f2b(s);
      else                     Cbb[row * DSTATE + (c - DINNER - DSTATE)] = f2b(s);
    }
  }
  if (threadIdx.x < NHEADS) {
    int hh = threadIdx.x;
    float raw = b2f(zx[(size_t)row * DINPROJ + DINNER + CONVDIM + hh]) + dtbias[hh];
    float dt = raw > 20.f ? raw : log1pf(__expf(raw));   // softplus
    dtb[row * NHEADS + hh] = dt;
  }
}

// ---------------- wave inclusive prefix sum helper ----------------
__device__ __forceinline__ float wave_incl_prefix(float a, int lane) {
#pragma unroll
  for (int off = 1; off < 64; off <<= 1) {
    float o = __shfl_up(a, off);
    if (lane >= off) a += o;
  }
  return a;
}

// ---------------- SSD phase A: chunk end-state S = Xw^T @ B, decay P ----------------
__global__ __launch_bounds__(64)
void chunk_state_kernel(const bf16* __restrict__ xbc, const bf16* __restrict__ Bb,
                        const float* __restrict__ dtb, const float* __restrict__ A_log,
                        float* __restrict__ Sbuf, float* __restrict__ Pbuf)
{
  const int blk = blockIdx.x;
  const int c = blk & 31, h = (blk >> 5) & 31, b = blk >> 10;
  const int bh = b * 32 + h;
  const int lane = threadIdx.x;              // = s (timestep within chunk)
  const int row = b * SEQLEN + c * 64 + lane;
  const float Ah = -__expf(A_log[h]);

  float dts = dtb[row * NHEADS + h];
  float E = wave_incl_prefix(dts * Ah, lane);
  float EQ = __shfl(E, 63);
  float w = __expf(EQ - E) * dts;
  if (lane == 63) Pbuf[bh * NCHUNK + c] = __expf(EQ);

  __shared__ __align__(16) short XwT[64 * 72];   // [p][s] pad 72
  __shared__ __align__(16) short BT[64 * 72];    // [n][s] pad 72

  const bf16* xrow = xbc + (size_t)row * CONVDIM + h * 64;
  const bf16* brow = Bb + (size_t)row * DSTATE;
#pragma unroll
  for (int i = 0; i < 8; ++i) {
    short8 xv = *(const short8*)(xrow + i * 8);
    short8 bv = *(const short8*)(brow + i * 8);
#pragma unroll
    for (int j = 0; j < 8; ++j) {
      XwT[(i * 8 + j) * 72 + lane] = f2s(w * s2f(xv[j]));
      BT[(i * 8 + j) * 72 + lane]  = bv[j];
    }
  }
  __syncthreads();

  const int r16 = lane & 15, q = lane >> 4;
  floatx4 acc[4][4] = {};
#pragma unroll
  for (int kk = 0; kk < 64; kk += 32) {
    short8 af[4], bfr[4];
#pragma unroll
    for (int i = 0; i < 4; ++i) af[i]  = *(const short8*)&XwT[(i * 16 + r16) * 72 + kk + q * 8];
#pragma unroll
    for (int j = 0; j < 4; ++j) bfr[j] = *(const short8*)&BT[(j * 16 + r16) * 72 + kk + q * 8];
#pragma unroll
    for (int i = 0; i < 4; ++i)
#pragma unroll
      for (int j = 0; j < 4; ++j)
        acc[i][j] = __builtin_amdgcn_mfma_f32_16x16x32_bf16(af[i], bfr[j], acc[i][j], 0, 0, 0);
  }
  float* Sout = Sbuf + (size_t)(bh * NCHUNK + c) * 4096;
#pragma unroll
  for (int i = 0; i < 4; ++i)
#pragma unroll
    for (int j = 0; j < 4; ++j)
#pragma unroll
      for (int r = 0; r < 4; ++r)
        Sout[(i * 16 + q * 4 + r) * 64 + (j * 16 + r16)] = acc[i][j][r];
}

// ---------------- SSD phase B: serial chunk combine (scalar decay) ----------------
__global__ __launch_bounds__(64)
void combine_kernel(const float* __restrict__ Sbuf, const float* __restrict__ Pbuf,
                    bf16* __restrict__ HinB)
{
  const int bh = blockIdx.x >> 2, slab = blockIdx.x & 3;
  const int base = slab * 1024 + threadIdx.x * 16;
  float h[16];
#pragma unroll
  for (int k = 0; k < 16; ++k) h[k] = 0.f;
  for (int c = 0; c < NCHUNK; ++c) {
    size_t off = (size_t)(bh * NCHUNK + c) * 4096 + base;
    union { short s[16]; uint4 q[2]; } pk;
#pragma unroll
    for (int k = 0; k < 16; ++k) pk.s[k] = f2s(h[k]);
    *(uint4*)(HinB + off)     = pk.q[0];
    *(uint4*)(HinB + off + 8) = pk.q[1];
    float P = Pbuf[bh * NCHUNK + c];
    const float4* S4 = (const float4*)(Sbuf + off);
#pragma unroll
    for (int k = 0; k < 4; ++k) {
      float4 s = S4[k];
      h[k*4+0] = h[k*4+0] * P + s.x;
      h[k*4+1] = h[k*4+1] * P + s.y;
      h[k*4+2] = h[k*4+2] * P + s.z;
      h[k*4+3] = h[k*4+3] * P + s.w;
    }
  }
}

// ---------------- SSD phase C: Y = (mask ⊙ C B^T) @ Xdt + (e^E C) @ Hin^T + D x ----------------
__global__ __launch_bounds__(64)
void y_kernel(const bf16* __restrict__ xbc, const bf16* __restrict__ Bb,
              const bf16* __restrict__ Cbb, const float* __restrict__ dtb,
              const bf16* __restrict__ HinB, const float* __restrict__ A_log,
              const float* __restrict__ Dp, bf16* __restrict__ yout)
{
  const int blk = blockIdx.x;
  const int c = blk & 31, h = (blk >> 5) & 31, b = blk >> 10;
  const int bh = b * 32 + h;
  const int lane = threadIdx.x;              // = s for the builds
  const int row0 = b * SEQLEN + c * 64;
  const int row = row0 + lane;
  const float Ah = -__expf(A_log[h]);
  const float Dh = Dp[h];

  __shared__ __align__(16) short XdT[64 * 72];  // [p][s]
  __shared__ __align__(16) short Msh[64 * 72];  // [t][s]
  __shared__ float Esh[64];

  float dts = dtb[row * NHEADS + h];
  float E = wave_incl_prefix(dts * Ah, lane);
  Esh[lane] = E;

  const bf16* xrow = xbc + (size_t)row * CONVDIM + h * 64;
#pragma unroll
  for (int i = 0; i < 8; ++i) {
    short8 xv = *(const short8*)(xrow + i * 8);
#pragma unroll
    for (int j = 0; j < 8; ++j)
      XdT[(i * 8 + j) * 72 + lane] = f2s(dts * s2f(xv[j]));
  }
  __syncthreads();

  const int r16 = lane & 15, q = lane >> 4;

  // G = C @ B^T  (t x s)
  floatx4 accg[4][4] = {};
#pragma unroll
  for (int kk = 0; kk < 64; kk += 32) {
    short8 af[4], bfr[4];
#pragma unroll
    for (int i = 0; i < 4; ++i)
      af[i]  = *(const short8*)(Cbb + (size_t)(row0 + i * 16 + r16) * DSTATE + kk + q * 8);
#pragma unroll
    for (int j = 0; j < 4; ++j)
      bfr[j] = *(const short8*)(Bb + (size_t)(row0 + j * 16 + r16) * DSTATE + kk + q * 8);
#pragma unroll
    for (int i = 0; i < 4; ++i)
#pragma unroll
      for (int j = 0; j < 4; ++j)
        accg[i][j] = __builtin_amdgcn_mfma_f32_16x16x32_bf16(af[i], bfr[j], accg[i][j], 0, 0, 0);
  }
  // causal decay mask -> Msh (bf16, A-operand layout for next MFMA)
#pragma unroll
  for (int i = 0; i < 4; ++i)
#pragma unroll
    for (int j = 0; j < 4; ++j)
#pragma unroll
      for (int r = 0; r < 4; ++r) {
        int t = i * 16 + q * 4 + r;
        int s = j * 16 + r16;
        float v = (s <= t) ? __expf(Esh[t] - Esh[s]) * accg[i][j][r] : 0.f;
        Msh[t * 72 + s] = f2s(v);
      }
  __syncthreads();

  floatx4 acc[4][4] = {};
  // Y_intra = M @ Xdt   (t x p)
#pragma unroll
  for (int kk = 0; kk < 64; kk += 32) {
    short8 af[4], bfr[4];
#pragma unroll
    for (int i = 0; i < 4; ++i) af[i]  = *(const short8*)&Msh[(i * 16 + r16) * 72 + kk + q * 8];
#pragma unroll
    for (int j = 0; j < 4; ++j) bfr[j] = *(const short8*)&XdT[(j * 16 + r16) * 72 + kk + q * 8];
#pragma unroll
    for (int i = 0; i < 4; ++i)
#pragma unroll
      for (int j = 0; j < 4; ++j)
        acc[i][j] = __builtin_amdgcn_mfma_f32_16x16x32_bf16(af[i], bfr[j], acc[i][j], 0, 0, 0);
  }
  // Y_inter = (e^{E_t} C) @ Hin^T   (t x p)
  float ei[4];
#pragma unroll
  for (int i = 0; i < 4; ++i) ei[i] = __expf(Esh[i * 16 + r16]);
  const bf16* hinp = HinB + (size_t)(bh * NCHUNK + c) * 4096;
#pragma unroll
  for (int kk = 0; kk < 64; kk += 32) {
    short8 af[4], bfr[4];
#pragma unroll
    for (int i = 0; i < 4; ++i) {
      short8 cv = *(const short8*)(Cbb + (size_t)(row0 + i * 16 + r16) * DSTATE + kk + q * 8);
#pragma unroll
      for (int jj = 0; jj < 8; ++jj) af[i][jj] = f2s(ei[i] * s2f(cv[jj]));
    }
#pragma unroll
    for (int j = 0; j < 4; ++j)
      bfr[j] = *(const short8*)(hinp + (j * 16 + r16) * 64 + kk + q * 8);
#pragma unroll
    for (int i = 0; i < 4; ++i)
#pragma unroll
      for (int j = 0; j < 4; ++j)
        acc[i][j] = __builtin_amdgcn_mfma_f32_16x16x32_bf16(af[i], bfr[j], acc[i][j], 0, 0, 0);
  }
  // epilogue: + D * x, store bf16
#pragma unroll
  for (int i = 0; i < 4; ++i)
#pragma unroll
    for (int j = 0; j < 4; ++j)
#pragma unroll
      for (int r = 0; r < 4; ++r) {
        int t = i * 16 + q * 4 + r;
        int p = j * 16 + r16;
        int g = row0 + t;
        float y = acc[i][j][r] + Dh * b2f(xbc[(size_t)g * CONVDIM + h * 64 + p]);
        yout[(size_t)g * DINNER + h * 64 + p] = f2b(y);
      }
}

// ---------------- gate (y * silu(z)) + RMSNorm ----------------
__global__ void gate_rms_kernel(const bf16* __restrict__ y, const bf16* __restrict__ zx,
                                const float* __restrict__ nw, bf16* __restrict__ yn)
{
  int row = blockIdx.x, tid = threadIdx.x;
  float v[8]; float ss = 0.f, dummy = 0.f;
#pragma unroll
  for (int k = 0; k < 8; ++k) {
    int c = k * 256 + tid;
    float z = b2f(zx[(size_t)row * DINPROJ + c]);
    float g = z / (1.f + __expf(-z));
    float val = b2f(y[(size_t)row * DINNER + c]) * g;
    v[k] = val; ss += val * val;
  }
  block_reduce_2(ss, dummy);
  float rs = rsqrtf(ss * (1.f / DINNER) + 1e-5f);
#pragma unroll
  for (int k = 0; k < 8; ++k) {
    int c = k * 256 + tid;
    yn[(size_t)row * DINNER + c] = f2b(v[k] * rs * nw[c]);
  }
}

extern "C" void kernel_launch(void* const* d_in, const int* in_sizes, int n_in,
                              void* d_out, int out_size, void* d_ws, size_t ws_size,
                              hipStream_t stream)
{
  const float* x         = (const float*)d_in[0];
  const float* ln1_w     = (const float*)d_in[1];
  const float* ln1_b     = (const float*)d_in[2];
  const float* in_proj_w = (const float*)d_in[3];
  const float* conv_w    = (const float*)d_in[4];
  const float* conv_b    = (const float*)d_in[5];
  const float* dt_bias   = (const float*)d_in[6];
  const float* A_log     = (const float*)d_in[7];
  const float* Dp        = (const float*)d_in[8];
  const float* norm_w    = (const float*)d_in[9];
  const float* out_proj_w= (const float*)d_in[10];
  const float* ln2_w     = (const float*)d_in[11];
  const float* ln2_b     = (const float*)d_in[12];
  const float* mlp_w1    = (const float*)d_in[13];
  const float* mlp_b1    = (const float*)d_in[14];
  const float* mlp_w2    = (const float*)d_in[15];
  const float* mlp_b2    = (const float*)d_in[16];

  char* ws = (char*)d_ws;
  bf16*  zx   = (bf16*)(ws + 0);            // 34,865,152
  bf16*  h1   = (bf16*)(ws + 34865152);     //  8,388,608
  bf16*  xbc  = (bf16*)(ws + 43253760);     // 17,825,792 (reused as w2b)
  bf16*  Bb   = (bf16*)(ws + 61079552);     //    524,288
  bf16*  Cbb  = (bf16*)(ws + 61603840);     //    524,288
  float* dtb  = (float*)(ws + 62128128);    //    524,288
  float* Pbuf = (float*)(ws + 62652416);    //      8,192
  float* Sbuf = (float*)(ws + 62660608);    // 33,554,432 fp32 (dead after combine)
  bf16*  yw   = (bf16*)(ws + 62660608);     // 16,777,216 bf16 (alias Sbuf lower; Sbuf dead)
  bf16*  x2   = (bf16*)(ws + 79437824);     //  8,388,608 bf16 (alias Sbuf upper; yw-disjoint)
  bf16*  HinB = (bf16*)(ws + 96215040);     //  8,388,608
  bf16*  yn   = (bf16*)(ws + 96215040);     // 16,777,216 (overlays HinB; HinB dead after y_kernel)
  bf16*  wip  = (bf16*)(ws + 112992256);    //  8,716,288 (reused as w1b)
  bf16*  wop  = (bf16*)(ws + 121708544);    //  4,194,304 -> end 125,902,848
  bf16*  h2n  = h1;
  bf16*  mid  = zx;
  bf16*  w1b  = wip;
  bf16*  w2b  = xbc;

  // 0a. convert in_proj_w to bf16
  cvt_kernel<<<(4256 * 1024 / 4 + 255) / 256, 256, 0, stream>>>(in_proj_w, wip, 4256 * 1024 / 4);
  // 1. LN1
  ln_kernel<float><<<ROWS, 256, 0, stream>>>(x, ln1_w, ln1_b, h1);
  // 2. in_proj   [grid x = M-tiles (32), y = N-tiles (34)]
  gemm_bt<0><<<dim3(32, 34), 256, 0, stream>>>(h1, wip, nullptr, nullptr, zx,
                                               ROWS, DINPROJ, DMODEL);
  // 0b. convert mlp_w1 (into wip region) and out_proj_w
  cvt_kernel<<<(4096 * 1024 / 4 + 255) / 256, 256, 0, stream>>>(mlp_w1, w1b, 4096 * 1024 / 4);
  cvt_kernel<<<(1024 * 2048 / 4 + 255) / 256, 256, 0, stream>>>(out_proj_w, wop, 1024 * 2048 / 4);
  // 3. conv + SiLU + softplus(dt)
  conv_kernel<<<ROWS, 256, 0, stream>>>(zx, conv_w, conv_b, dt_bias, xbc, Bb, Cbb, dtb);
  // 4a. SSD phase A: per-chunk end states
  chunk_state_kernel<<<2048, 64, 0, stream>>>(xbc, Bb, dtb, A_log, Sbuf, Pbuf);
  // 4b. SSD phase B: combine chunk states
  combine_kernel<<<256, 64, 0, stream>>>(Sbuf, Pbuf, HinB);
  // 4c. SSD phase C: outputs (bf16)
  y_kernel<<<2048, 64, 0, stream>>>(xbc, Bb, Cbb, dtb, HinB, A_log, Dp, yw);
  // 0c. convert mlp_w2 (xbc region dead now)
  cvt_kernel<<<(1024 * 4096 / 4 + 255) / 256, 256, 0, stream>>>(mlp_w2, w2b, 1024 * 4096 / 4);
  // 5. gate + RMSNorm
  gate_rms_kernel<<<ROWS, 256, 0, stream>>>(yw, zx, norm_w, yn);
  // 6. out_proj + residual(x, fp32) -> x2 (bf16)   [64x64 tile, 1024 blocks]
  gemm_bt_6464<2><<<dim3(64, 16), 256, 0, stream>>>(yn, wop, nullptr, x, (void*)x2,
                                                    ROWS, DMODEL, DINNER);
  // 7. LN2 (bf16 in)
  ln_kernel<bf16><<<ROWS, 256, 0, stream>>>(x2, ln2_w, ln2_b, h2n);
  // 8. mlp1 + bias + GELU   [grid x = M-tiles (32), y = N-tiles (32)]
  gemm_bt<1><<<dim3(32, 32), 256, 0, stream>>>(h2n, w1b, mlp_b1, nullptr, mid,
                                               ROWS, 4 * DMODEL, DMODEL);
  // 9. mlp2 + bias + residual(x2, bf16) -> out (fp32)   [64x64 tile, 1024 blocks]
  gemm_bt_6464<3><<<dim3(64, 16), 256, 0, stream>>>(mid, w2b, mlp_b2, x2, d_out,
                                                    ROWS, DMODEL, 4 * DMODEL);
}

// Round 7
// 427.402 us; speedup vs baseline: 1.2726x; 1.1019x over previous
//
#include <hip/hip_runtime.h>
#include <hip/hip_bf16.h>
#include <math.h>

using bf16 = __hip_bfloat16;
typedef __attribute__((ext_vector_type(8))) short short8;
typedef __attribute__((ext_vector_type(4))) float floatx4;

#define SEQLEN   2048
#define ROWS     4096      // B*L
#define DMODEL   1024
#define DINNER   2048
#define NHEADS   32
#define HEADDIM  64
#define DSTATE   64
#define CONVDIM  2176
#define DINPROJ  4256
#define NCHUNK   32        // 2048 / 64

__device__ __forceinline__ float b2f(bf16 x) { return __bfloat162float(x); }
__device__ __forceinline__ bf16  f2b(float x) { return __float2bfloat16(x); }
__device__ __forceinline__ float s2f(short s) { union { short s; bf16 b; } u; u.s = s; return b2f(u.b); }
__device__ __forceinline__ short f2s(float f) { union { short s; bf16 b; } u; u.b = f2b(f); return u.s; }
__device__ __forceinline__ float tof(float x) { return x; }
__device__ __forceinline__ float tof(bf16 x)  { return __bfloat162float(x); }

// ---------------- async global->LDS (16B per lane) ----------------
typedef __attribute__((address_space(1))) void v_as1;
typedef __attribute__((address_space(3))) void v_as3;
__device__ __forceinline__ void gload_lds16(const void* g, void* l) {
  __builtin_amdgcn_global_load_lds((v_as1*)(g), (v_as3*)(l), 16, 0, 0);
}

// ---------------- fp32 -> bf16 conversion (4 elems/thread) ----------------
__global__ void cvt_kernel(const float* __restrict__ in, bf16* __restrict__ out, int n4) {
  int i = blockIdx.x * 256 + threadIdx.x;
  if (i < n4) {
    float4 v = ((const float4*)in)[i];
    union { bf16 h[4]; uint2 u; } r;
    r.h[0] = f2b(v.x); r.h[1] = f2b(v.y); r.h[2] = f2b(v.z); r.h[3] = f2b(v.w);
    ((uint2*)out)[i] = r.u;
  }
}

// ---------------- block reduction (2 values, 256 threads) ----------------
__device__ __forceinline__ void block_reduce_2(float& a, float& b) {
#pragma unroll
  for (int off = 32; off > 0; off >>= 1) {
    a += __shfl_xor(a, off);
    b += __shfl_xor(b, off);
  }
  __shared__ float ra[4], rb[4];
  int w = threadIdx.x >> 6;
  if ((threadIdx.x & 63) == 0) { ra[w] = a; rb[w] = b; }
  __syncthreads();
  a = ra[0] + ra[1] + ra[2] + ra[3];
  b = rb[0] + rb[1] + rb[2] + rb[3];
}

// ---------------- LayerNorm (1024 cols, fp32/bf16 in, bf16 out) ----------------
template<typename TIN>
__global__ void ln_kernel(const TIN* __restrict__ x, const float* __restrict__ w,
                          const float* __restrict__ b, bf16* __restrict__ out)
{
  int row = blockIdx.x;
  int tid = threadIdx.x;
  float v[4]; float s = 0.f, sq = 0.f;
#pragma unroll
  for (int k = 0; k < 4; ++k) {
    int c = k * 256 + tid;
    float xv = tof(x[(size_t)row * DMODEL + c]);
    v[k] = xv; s += xv; sq += xv * xv;
  }
  block_reduce_2(s, sq);
  float mu  = s * (1.f / DMODEL);
  float var = sq * (1.f / DMODEL) - mu * mu;
  float rs  = rsqrtf(var + 1e-5f);
#pragma unroll
  for (int k = 0; k < 4; ++k) {
    int c = k * 256 + tid;
    out[(size_t)row * DMODEL + c] = f2b((v[k] - mu) * rs * w[c] + b[c]);
  }
}

// ---------------- epilogue helper ----------------
// EPI 0: store bf16
// EPI 1: +bias(fp32), exact GELU, store bf16
// EPI 2: +resid(fp32), store bf16
// EPI 3: +bias(fp32) +resid(bf16), store fp32
template<int EPI>
__device__ __forceinline__ void epi_store(float v, size_t off, int col,
                                          const float* bias, const void* resid, void* Cout)
{
  if (EPI == 0) {
    ((bf16*)Cout)[off] = f2b(v);
  } else if (EPI == 1) {
    v += bias[col];
    v = 0.5f * v * (1.f + erff(v * 0.70710678118654752f));
    ((bf16*)Cout)[off] = f2b(v);
  } else if (EPI == 2) {
    v += ((const float*)resid)[off];
    ((bf16*)Cout)[off] = f2b(v);
  } else {
    v += bias[col] + b2f(((const bf16*)resid)[off]);
    ((float*)Cout)[off] = v;
  }
}

// XOR-swizzle: LDS slot (row, blk16) holds global block (blk16 ^ (row&7)).
// Staging keeps global_load_lds's contiguous lane->LDS mapping; readers XOR too.
// Breaks the 128B-row bank aliasing: a q-group's 16 rows spread over all 8 blocks.

// ---------------- GEMM 128x128 tile; blockIdx.x = M-tile (XCD affinity on A rows) ----------------
template<int EPI>
__global__ __launch_bounds__(256, 2)
void gemm_bt(const bf16* __restrict__ A, const bf16* __restrict__ W,
             const float* __restrict__ bias, const void* __restrict__ resid,
             void* __restrict__ Cout, int M, int N, int K)
{
  __shared__ __align__(16) short Asl[128 * 64];
  __shared__ __align__(16) short Bsl[128 * 64];
  const int tid  = threadIdx.x;
  const int lane = tid & 63;
  const int wv   = tid >> 6;
  const int wm   = wv >> 1, wn = wv & 1;
  const int r16  = lane & 15, q = lane >> 4;
  const int m0   = blockIdx.x * 128;   // x = M-tile: same-A-rows pin to one XCD
  const int n0   = blockIdx.y * 128;

  floatx4 acc[4][4] = {};

  for (int k0 = 0; k0 < K; k0 += 64) {
#pragma unroll
    for (int it = 0; it < 4; ++it) {
      int idx = it * 256 + tid;
      int row = m0 + (idx >> 3);
      int cb  = (((idx & 7) ^ ((idx >> 3) & 7)) << 3);   // swizzled source block
      gload_lds16(A + (size_t)row * K + k0 + cb, &Asl[idx * 8]);
    }
#pragma unroll
    for (int it = 0; it < 4; ++it) {
      int idx = it * 256 + tid;
      int row = n0 + (idx >> 3);
      if (row > N - 1) row = N - 1;
      int cb  = (((idx & 7) ^ ((idx >> 3) & 7)) << 3);
      gload_lds16(W + (size_t)row * K + k0 + cb, &Bsl[idx * 8]);
    }
    __syncthreads();
#pragma unroll
    for (int kk = 0; kk < 64; kk += 32) {
      short8 af[4], bfr[4];
      const int lb = (kk >> 3) + q;                       // logical 16B block 0..7
#pragma unroll
      for (int i = 0; i < 4; ++i) {
        int ar = wm * 64 + i * 16 + r16;
        af[i] = *(const short8*)&Asl[ar * 64 + ((lb ^ (ar & 7)) << 3)];
      }
#pragma unroll
      for (int j = 0; j < 4; ++j) {
        int br = wn * 64 + j * 16 + r16;
        bfr[j] = *(const short8*)&Bsl[br * 64 + ((lb ^ (br & 7)) << 3)];
      }
#pragma unroll
      for (int i = 0; i < 4; ++i)
#pragma unroll
        for (int j = 0; j < 4; ++j)
          acc[i][j] = __builtin_amdgcn_mfma_f32_16x16x32_bf16(af[i], bfr[j], acc[i][j], 0, 0, 0);
    }
    __syncthreads();
  }

#pragma unroll
  for (int i = 0; i < 4; ++i)
#pragma unroll
    for (int j = 0; j < 4; ++j)
#pragma unroll
      for (int r = 0; r < 4; ++r) {
        int row = m0 + wm * 64 + i * 16 + q * 4 + r;
        int col = n0 + wn * 64 + j * 16 + r16;
        if (col < N)
          epi_store<EPI>(acc[i][j][r], (size_t)row * N + col, col, bias, resid, Cout);
      }
}

// ---------------- GEMM 64x64 tile (N=1024 GEMMs): 1024 blocks = 4/CU, 16 KB LDS ----------------
template<int EPI>
__global__ __launch_bounds__(256, 4)
void gemm_bt_6464(const bf16* __restrict__ A, const bf16* __restrict__ W,
                  const float* __restrict__ bias, const void* __restrict__ resid,
                  void* __restrict__ Cout, int M, int N, int K)
{
  __shared__ __align__(16) short Asl[64 * 64];    // 8 KB
  __shared__ __align__(16) short Bsl[64 * 64];    // 8 KB
  const int tid  = threadIdx.x;
  const int lane = tid & 63;
  const int wv   = tid >> 6;
  const int wm   = wv >> 1, wn = wv & 1;          // 2x2 wave grid of 32x32 sub-tiles
  const int r16  = lane & 15, q = lane >> 4;
  const int m0   = blockIdx.x * 64;               // x = M-tile: XCD pin on A rows
  const int n0   = blockIdx.y * 64;

  floatx4 acc[2][2] = {};

  for (int k0 = 0; k0 < K; k0 += 64) {
#pragma unroll
    for (int it = 0; it < 2; ++it) {
      int idx = it * 256 + tid;
      int cb  = (((idx & 7) ^ ((idx >> 3) & 7)) << 3);
      gload_lds16(A + (size_t)(m0 + (idx >> 3)) * K + k0 + cb, &Asl[idx * 8]);
    }
#pragma unroll
    for (int it = 0; it < 2; ++it) {
      int idx = it * 256 + tid;
      int cb  = (((idx & 7) ^ ((idx >> 3) & 7)) << 3);
      gload_lds16(W + (size_t)(n0 + (idx >> 3)) * K + k0 + cb, &Bsl[idx * 8]);
    }
    __syncthreads();
#pragma unroll
    for (int kk = 0; kk < 64; kk += 32) {
      short8 af[2], bfr[2];
      const int lb = (kk >> 3) + q;
#pragma unroll
      for (int i = 0; i < 2; ++i) {
        int ar = wm * 32 + i * 16 + r16;
        af[i] = *(const short8*)&Asl[ar * 64 + ((lb ^ (ar & 7)) << 3)];
      }
#pragma unroll
      for (int j = 0; j < 2; ++j) {
        int br = wn * 32 + j * 16 + r16;
        bfr[j] = *(const short8*)&Bsl[br * 64 + ((lb ^ (br & 7)) << 3)];
      }
#pragma unroll
      for (int i = 0; i < 2; ++i)
#pragma unroll
        for (int j = 0; j < 2; ++j)
          acc[i][j] = __builtin_amdgcn_mfma_f32_16x16x32_bf16(af[i], bfr[j], acc[i][j], 0, 0, 0);
    }
    __syncthreads();
  }

#pragma unroll
  for (int i = 0; i < 2; ++i)
#pragma unroll
    for (int j = 0; j < 2; ++j)
#pragma unroll
      for (int r = 0; r < 4; ++r) {
        int row = m0 + wm * 32 + i * 16 + q * 4 + r;
        int col = n0 + wn * 32 + j * 16 + r16;
        epi_store<EPI>(acc[i][j][r], (size_t)row * N + col, col, bias, resid, Cout);
      }
}

// ---------------- depthwise causal conv (4 tap) + SiLU + softplus(dt) ----------------
__global__ void conv_kernel(const bf16* __restrict__ zx, const float* __restrict__ cw,
                            const float* __restrict__ cb, const float* __restrict__ dtbias,
                            bf16* __restrict__ xbc, bf16* __restrict__ Bb,
                            bf16* __restrict__ Cbb, float* __restrict__ dtb)
{
  int row = blockIdx.x;
  int b = row >> 11, t = row & 2047;
  for (int c = threadIdx.x; c < CONVDIM; c += 256) {
    float acc = cb[c];
#pragma unroll
    for (int k = 0; k < 4; ++k) {
      int tt = t + k - 3;
      if (tt >= 0)
        acc += b2f(zx[((size_t)(b * SEQLEN + tt)) * DINPROJ + DINNER + c]) * cw[c * 4 + k];
    }
    float s = acc / (1.f + __expf(-acc));   // SiLU
    xbc[(size_t)row * CONVDIM + c] = f2b(s);
    if (c >= DINNER) {
      if (c < DINNER + DSTATE) Bb[row * DSTATE + (c - DINNER)] = f2b(s);
      else                     Cbb[row * DSTATE + (c - DINNER - DSTATE)] = f2b(s);
    }
  }
  if (threadIdx.x < NHEADS) {
    int hh = threadIdx.x;
    float raw = b2f(zx[(size_t)row * DINPROJ + DINNER + CONVDIM + hh]) + dtbias[hh];
    float dt = raw > 20.f ? raw : log1pf(__expf(raw));   // softplus
    dtb[row * NHEADS + hh] = dt;
  }
}

// ---------------- wave inclusive prefix sum helper ----------------
__device__ __forceinline__ float wave_incl_prefix(float a, int lane) {
#pragma unroll
  for (int off = 1; off < 64; off <<= 1) {
    float o = __shfl_up(a, off);
    if (lane >= off) a += o;
  }
  return a;
}

// ---------------- SSD phase A: chunk end-state S = Xw^T @ B, decay P ----------------
__global__ __launch_bounds__(64)
void chunk_state_kernel(const bf16* __restrict__ xbc, const bf16* __restrict__ Bb,
                        const float* __restrict__ dtb, const float* __restrict__ A_log,
                        float* __restrict__ Sbuf, float* __restrict__ Pbuf)
{
  const int blk = blockIdx.x;
  const int c = blk & 31, h = (blk >> 5) & 31, b = blk >> 10;
  const int bh = b * 32 + h;
  const int lane = threadIdx.x;              // = s (timestep within chunk)
  const int row = b * SEQLEN + c * 64 + lane;
  const float Ah = -__expf(A_log[h]);

  float dts = dtb[row * NHEADS + h];
  float E = wave_incl_prefix(dts * Ah, lane);
  float EQ = __shfl(E, 63);
  float w = __expf(EQ - E) * dts;
  if (lane == 63) Pbuf[bh * NCHUNK + c] = __expf(EQ);

  __shared__ __align__(16) short XwT[64 * 72];   // [p][s] pad 72
  __shared__ __align__(16) short BT[64 * 72];    // [n][s] pad 72

  const bf16* xrow = xbc + (size_t)row * CONVDIM + h * 64;
  const bf16* brow = Bb + (size_t)row * DSTATE;
#pragma unroll
  for (int i = 0; i < 8; ++i) {
    short8 xv = *(const short8*)(xrow + i * 8);
    short8 bv = *(const short8*)(brow + i * 8);
#pragma unroll
    for (int j = 0; j < 8; ++j) {
      XwT[(i * 8 + j) * 72 + lane] = f2s(w * s2f(xv[j]));
      BT[(i * 8 + j) * 72 + lane]  = bv[j];
    }
  }
  __syncthreads();

  const int r16 = lane & 15, q = lane >> 4;
  floatx4 acc[4][4] = {};
#pragma unroll
  for (int kk = 0; kk < 64; kk += 32) {
    short8 af[4], bfr[4];
#pragma unroll
    for (int i = 0; i < 4; ++i) af[i]  = *(const short8*)&XwT[(i * 16 + r16) * 72 + kk + q * 8];
#pragma unroll
    for (int j = 0; j < 4; ++j) bfr[j] = *(const short8*)&BT[(j * 16 + r16) * 72 + kk + q * 8];
#pragma unroll
    for (int i = 0; i < 4; ++i)
#pragma unroll
      for (int j = 0; j < 4; ++j)
        acc[i][j] = __builtin_amdgcn_mfma_f32_16x16x32_bf16(af[i], bfr[j], acc[i][j], 0, 0, 0);
  }
  float* Sout = Sbuf + (size_t)(bh * NCHUNK + c) * 4096;
#pragma unroll
  for (int i = 0; i < 4; ++i)
#pragma unroll
    for (int j = 0; j < 4; ++j)
#pragma unroll
      for (int r = 0; r < 4; ++r)
        Sout[(i * 16 + q * 4 + r) * 64 + (j * 16 + r16)] = acc[i][j][r];
}

// ---------------- SSD phase B: serial chunk combine (scalar decay) ----------------
__global__ __launch_bounds__(64)
void combine_kernel(const float* __restrict__ Sbuf, const float* __restrict__ Pbuf,
                    bf16* __restrict__ HinB)
{
  const int bh = blockIdx.x >> 2, slab = blockIdx.x & 3;
  const int base = slab * 1024 + threadIdx.x * 16;
  float h[16];
#pragma unroll
  for (int k = 0; k < 16; ++k) h[k] = 0.f;
  for (int c = 0; c < NCHUNK; ++c) {
    size_t off = (size_t)(bh * NCHUNK + c) * 4096 + base;
    union { short s[16]; uint4 q[2]; } pk;
#pragma unroll
    for (int k = 0; k < 16; ++k) pk.s[k] = f2s(h[k]);
    *(uint4*)(HinB + off)     = pk.q[0];
    *(uint4*)(HinB + off + 8) = pk.q[1];
    float P = Pbuf[bh * NCHUNK + c];
    const float4* S4 = (const float4*)(Sbuf + off);
#pragma unroll
    for (int k = 0; k < 4; ++k) {
      float4 s = S4[k];
      h[k*4+0] = h[k*4+0] * P + s.x;
      h[k*4+1] = h[k*4+1] * P + s.y;
      h[k*4+2] = h[k*4+2] * P + s.z;
      h[k*4+3] = h[k*4+3] * P + s.w;
    }
  }
}

// ---------------- SSD phase C: Y = (mask ⊙ C B^T) @ Xdt + (e^E C) @ Hin^T + D x ----------------
__global__ __launch_bounds__(64)
void y_kernel(const bf16* __restrict__ xbc, const bf16* __restrict__ Bb,
              const bf16* __restrict__ Cbb, const float* __restrict__ dtb,
              const bf16* __restrict__ HinB, const float* __restrict__ A_log,
              const float* __restrict__ Dp, bf16* __restrict__ yout)
{
  const int blk = blockIdx.x;
  const int c = blk & 31, h = (blk >> 5) & 31, b = blk >> 10;
  const int bh = b * 32 + h;
  const int lane = threadIdx.x;              // = s for the builds
  const int row0 = b * SEQLEN + c * 64;
  const int row = row0 + lane;
  const float Ah = -__expf(A_log[h]);
  const float Dh = Dp[h];

  __shared__ __align__(16) short XdT[64 * 72];  // [p][s]
  __shared__ __align__(16) short Msh[64 * 72];  // [t][s]
  __shared__ float Esh[64];

  float dts = dtb[row * NHEADS + h];
  float E = wave_incl_prefix(dts * Ah, lane);
  Esh[lane] = E;

  const bf16* xrow = xbc + (size_t)row * CONVDIM + h * 64;
#pragma unroll
  for (int i = 0; i < 8; ++i) {
    short8 xv = *(const short8*)(xrow + i * 8);
#pragma unroll
    for (int j = 0; j < 8; ++j)
      XdT[(i * 8 + j) * 72 + lane] = f2s(dts * s2f(xv[j]));
  }
  __syncthreads();

  const int r16 = lane & 15, q = lane >> 4;

  // G = C @ B^T  (t x s)
  floatx4 accg[4][4] = {};
#pragma unroll
  for (int kk = 0; kk < 64; kk += 32) {
    short8 af[4], bfr[4];
#pragma unroll
    for (int i = 0; i < 4; ++i)
      af[i]  = *(const short8*)(Cbb + (size_t)(row0 + i * 16 + r16) * DSTATE + kk + q * 8);
#pragma unroll
    for (int j = 0; j < 4; ++j)
      bfr[j] = *(const short8*)(Bb + (size_t)(row0 + j * 16 + r16) * DSTATE + kk + q * 8);
#pragma unroll
    for (int i = 0; i < 4; ++i)
#pragma unroll
      for (int j = 0; j < 4; ++j)
        accg[i][j] = __builtin_amdgcn_mfma_f32_16x16x32_bf16(af[i], bfr[j], accg[i][j], 0, 0, 0);
  }
  // causal decay mask -> Msh (bf16, A-operand layout for next MFMA)
#pragma unroll
  for (int i = 0; i < 4; ++i)
#pragma unroll
    for (int j = 0; j < 4; ++j)
#pragma unroll
      for (int r = 0; r < 4; ++r) {
        int t = i * 16 + q * 4 + r;
        int s = j * 16 + r16;
        float v = (s <= t) ? __expf(Esh[t] - Esh[s]) * accg[i][j][r] : 0.f;
        Msh[t * 72 + s] = f2s(v);
      }
  __syncthreads();

  floatx4 acc[4][4] = {};
  // Y_intra = M @ Xdt   (t x p)
#pragma unroll
  for (int kk = 0; kk < 64; kk += 32) {
    short8 af[4], bfr[4];
#pragma unroll
    for (int i = 0; i < 4; ++i) af[i]  = *(const short8*)&Msh[(i * 16 + r16) * 72 + kk + q * 8];
#pragma unroll
    for (int j = 0; j < 4; ++j) bfr[j] = *(const short8*)&XdT[(j * 16 + r16) * 72 + kk + q * 8];
#pragma unroll
    for (int i = 0; i < 4; ++i)
#pragma unroll
      for (int j = 0; j < 4; ++j)
        acc[i][j] = __builtin_amdgcn_mfma_f32_16x16x32_bf16(af[i], bfr[j], acc[i][j], 0, 0, 0);
  }
  // Y_inter = (e^{E_t} C) @ Hin^T   (t x p)
  float ei[4];
#pragma unroll
  for (int i = 0; i < 4; ++i) ei[i] = __expf(Esh[i * 16 + r16]);
  const bf16* hinp = HinB + (size_t)(bh * NCHUNK + c) * 4096;
#pragma unroll
  for (int kk = 0; kk < 64; kk += 32) {
    short8 af[4], bfr[4];
#pragma unroll
    for (int i = 0; i < 4; ++i) {
      short8 cv = *(const short8*)(Cbb + (size_t)(row0 + i * 16 + r16) * DSTATE + kk + q * 8);
#pragma unroll
      for (int jj = 0; jj < 8; ++jj) af[i][jj] = f2s(ei[i] * s2f(cv[jj]));
    }
#pragma unroll
    for (int j = 0; j < 4; ++j)
      bfr[j] = *(const short8*)(hinp + (j * 16 + r16) * 64 + kk + q * 8);
#pragma unroll
    for (int i = 0; i < 4; ++i)
#pragma unroll
      for (int j = 0; j < 4; ++j)
        acc[i][j] = __builtin_amdgcn_mfma_f32_16x16x32_bf16(af[i], bfr[j], acc[i][j], 0, 0, 0);
  }
  // epilogue: + D * x, store bf16
#pragma unroll
  for (int i = 0; i < 4; ++i)
#pragma unroll
    for (int j = 0; j < 4; ++j)
#pragma unroll
      for (int r = 0; r < 4; ++r) {
        int t = i * 16 + q * 4 + r;
        int p = j * 16 + r16;
        int g = row0 + t;
        float y = acc[i][j][r] + Dh * b2f(xbc[(size_t)g * CONVDIM + h * 64 + p]);
        yout[(size_t)g * DINNER + h * 64 + p] = f2b(y);
      }
}

// ---------------- gate (y * silu(z)) + RMSNorm ----------------
__global__ void gate_rms_kernel(const bf16* __restrict__ y, const bf16* __restrict__ zx,
                                const float* __restrict__ nw, bf16* __restrict__ yn)
{
  int row = blockIdx.x, tid = threadIdx.x;
  float v[8]; float ss = 0.f, dummy = 0.f;
#pragma unroll
  for (int k = 0; k < 8; ++k) {
    int c = k * 256 + tid;
    float z = b2f(zx[(size_t)row * DINPROJ + c]);
    float g = z / (1.f + __expf(-z));
    float val = b2f(y[(size_t)row * DINNER + c]) * g;
    v[k] = val; ss += val * val;
  }
  block_reduce_2(ss, dummy);
  float rs = rsqrtf(ss * (1.f / DINNER) + 1e-5f);
#pragma unroll
  for (int k = 0; k < 8; ++k) {
    int c = k * 256 + tid;
    yn[(size_t)row * DINNER + c] = f2b(v[k] * rs * nw[c]);
  }
}

extern "C" void kernel_launch(void* const* d_in, const int* in_sizes, int n_in,
                              void* d_out, int out_size, void* d_ws, size_t ws_size,
                              hipStream_t stream)
{
  const float* x         = (const float*)d_in[0];
  const float* ln1_w     = (const float*)d_in[1];
  const float* ln1_b     = (const float*)d_in[2];
  const float* in_proj_w = (const float*)d_in[3];
  const float* conv_w    = (const float*)d_in[4];
  const float* conv_b    = (const float*)d_in[5];
  const float* dt_bias   = (const float*)d_in[6];
  const float* A_log     = (const float*)d_in[7];
  const float* Dp        = (const float*)d_in[8];
  const float* norm_w    = (const float*)d_in[9];
  const float* out_proj_w= (const float*)d_in[10];
  const float* ln2_w     = (const float*)d_in[11];
  const float* ln2_b     = (const float*)d_in[12];
  const float* mlp_w1    = (const float*)d_in[13];
  const float* mlp_b1    = (const float*)d_in[14];
  const float* mlp_w2    = (const float*)d_in[15];
  const float* mlp_b2    = (const float*)d_in[16];

  char* ws = (char*)d_ws;
  bf16*  zx   = (bf16*)(ws + 0);            // 34,865,152
  bf16*  h1   = (bf16*)(ws + 34865152);     //  8,388,608
  bf16*  xbc  = (bf16*)(ws + 43253760);     // 17,825,792 (reused as w2b)
  bf16*  Bb   = (bf16*)(ws + 61079552);     //    524,288
  bf16*  Cbb  = (bf16*)(ws + 61603840);     //    524,288
  float* dtb  = (float*)(ws + 62128128);    //    524,288
  float* Pbuf = (float*)(ws + 62652416);    //      8,192
  float* Sbuf = (float*)(ws + 62660608);    // 33,554,432 fp32 (dead after combine)
  bf16*  yw   = (bf16*)(ws + 62660608);     // 16,777,216 bf16 (alias Sbuf lower; Sbuf dead)
  bf16*  x2   = (bf16*)(ws + 79437824);     //  8,388,608 bf16 (alias Sbuf upper; yw-disjoint)
  bf16*  HinB = (bf16*)(ws + 96215040);     //  8,388,608
  bf16*  yn   = (bf16*)(ws + 96215040);     // 16,777,216 (overlays HinB; HinB dead after y_kernel)
  bf16*  wip  = (bf16*)(ws + 112992256);    //  8,716,288 (reused as w1b)
  bf16*  wop  = (bf16*)(ws + 121708544);    //  4,194,304 -> end 125,902,848
  bf16*  h2n  = h1;
  bf16*  mid  = zx;
  bf16*  w1b  = wip;
  bf16*  w2b  = xbc;

  // 0a. convert in_proj_w to bf16
  cvt_kernel<<<(4256 * 1024 / 4 + 255) / 256, 256, 0, stream>>>(in_proj_w, wip, 4256 * 1024 / 4);
  // 1. LN1
  ln_kernel<float><<<ROWS, 256, 0, stream>>>(x, ln1_w, ln1_b, h1);
  // 2. in_proj   [grid x = M-tiles (32), y = N-tiles (34)]
  gemm_bt<0><<<dim3(32, 34), 256, 0, stream>>>(h1, wip, nullptr, nullptr, zx,
                                               ROWS, DINPROJ, DMODEL);
  // 0b. convert mlp_w1 (into wip region) and out_proj_w
  cvt_kernel<<<(4096 * 1024 / 4 + 255) / 256, 256, 0, stream>>>(mlp_w1, w1b, 4096 * 1024 / 4);
  cvt_kernel<<<(1024 * 2048 / 4 + 255) / 256, 256, 0, stream>>>(out_proj_w, wop, 1024 * 2048 / 4);
  // 3. conv + SiLU + softplus(dt)
  conv_kernel<<<ROWS, 256, 0, stream>>>(zx, conv_w, conv_b, dt_bias, xbc, Bb, Cbb, dtb);
  // 4a. SSD phase A: per-chunk end states
  chunk_state_kernel<<<2048, 64, 0, stream>>>(xbc, Bb, dtb, A_log, Sbuf, Pbuf);
  // 4b. SSD phase B: combine chunk states
  combine_kernel<<<256, 64, 0, stream>>>(Sbuf, Pbuf, HinB);
  // 4c. SSD phase C: outputs (bf16)
  y_kernel<<<2048, 64, 0, stream>>>(xbc, Bb, Cbb, dtb, HinB, A_log, Dp, yw);
  // 0c. convert mlp_w2 (xbc region dead now)
  cvt_kernel<<<(1024 * 4096 / 4 + 255) / 256, 256, 0, stream>>>(mlp_w2, w2b, 1024 * 4096 / 4);
  // 5. gate + RMSNorm
  gate_rms_kernel<<<ROWS, 256, 0, stream>>>(yw, zx, norm_w, yn);
  // 6. out_proj + residual(x, fp32) -> x2 (bf16)   [64x64 tile, 1024 blocks]
  gemm_bt_6464<2><<<dim3(64, 16), 256, 0, stream>>>(yn, wop, nullptr, x, (void*)x2,
                                                    ROWS, DMODEL, DINNER);
  // 7. LN2 (bf16 in)
  ln_kernel<bf16><<<ROWS, 256, 0, stream>>>(x2, ln2_w, ln2_b, h2n);
  // 8. mlp1 + bias + GELU   [grid x = M-tiles (32), y = N-tiles (32)]
  gemm_bt<1><<<dim3(32, 32), 256, 0, stream>>>(h2n, w1b, mlp_b1, nullptr, mid,
                                               ROWS, 4 * DMODEL, DMODEL);
  // 9. mlp2 + bias + residual(x2, bf16) -> out (fp32)   [64x64 tile, 1024 blocks]
  gemm_bt_6464<3><<<dim3(64, 16), 256, 0, stream>>>(mid, w2b, mlp_b2, x2, d_out,
                                                    ROWS, DMODEL, 4 * DMODEL);
}